// Round 1
// baseline (2416.384 us; speedup 1.0000x reference)
//
#include <hip/hip_runtime.h>
#include <hip/hip_bf16.h>

// PINN fused forward+jvp²: N=65536 samples, layers [1,20,50,200,500,200,100].
// One kernel; each block owns B=8 samples, activations (v,d,dd) live in LDS,
// weights stream from global (0.92 MB total -> L2 resident).

#define NSAMP 65536
#define Q 100
#define DTC 0.8f
#define B 8            // samples per block
#define BLOCK 256
#define OGN 32         // output groups = BLOCK / B

__device__ __forceinline__ float fast_tanh(float z) {
    float az = fabsf(z);
    float e  = __expf(-2.0f * az);
    float r  = __builtin_amdgcn_rcpf(1.0f + e);   // ~1ulp, fine vs 12.8 absmax
    float t  = (1.0f - e) * r;
    return copysignf(t, z);
}

// One dense layer applied to the 3 Taylor states held in LDS.
// ldsIn layout: [state][sample][k], row stride KP (padded to break bank aliasing)
// ldsOut layout: [state][sample][o], row stride FOUTP
template<int K, int KP, int FOUT, int FOUTP, bool TANH, int UO, int VEC>
__device__ __forceinline__ void layer(const float* __restrict__ W,
                                      const float* __restrict__ bias,
                                      const float* ldsIn, float* ldsOut,
                                      int s, int og) {
    const float* inv  = ldsIn + (0 * B + s) * KP;
    const float* ind  = ldsIn + (1 * B + s) * KP;
    const float* indd = ldsIn + (2 * B + s) * KP;

    for (int obase = 0; obase < FOUT; obase += OGN * UO) {
        float accv[UO], accd[UO], accdd[UO];
        const float* Wr[UO];
        int olist[UO];
#pragma unroll
        for (int u = 0; u < UO; ++u) {
            accv[u] = 0.f; accd[u] = 0.f; accdd[u] = 0.f;
            int o = obase + og + OGN * u;
            olist[u] = o;
            int oc = o < FOUT ? o : FOUT - 1;   // clamp: keeps k-loop branch-free
            Wr[u] = W + oc * K;
        }

        if constexpr (VEC == 4) {
#pragma unroll 2
            for (int k = 0; k < K; k += 4) {
                float4 av  = *(const float4*)(inv  + k);
                float4 ad  = *(const float4*)(ind  + k);
                float4 add = *(const float4*)(indd + k);
#pragma unroll
                for (int u = 0; u < UO; ++u) {
                    float4 w = *(const float4*)(Wr[u] + k);
                    accv[u]  += w.x * av.x  + w.y * av.y  + w.z * av.z  + w.w * av.w;
                    accd[u]  += w.x * ad.x  + w.y * ad.y  + w.z * ad.z  + w.w * ad.w;
                    accdd[u] += w.x * add.x + w.y * add.y + w.z * add.z + w.w * add.w;
                }
            }
        } else {  // VEC == 2 (K=50: 200 B rows are 8 B- but not 16 B-aligned)
#pragma unroll 2
            for (int k = 0; k < K; k += 2) {
                float2 av  = *(const float2*)(inv  + k);
                float2 ad  = *(const float2*)(ind  + k);
                float2 add = *(const float2*)(indd + k);
#pragma unroll
                for (int u = 0; u < UO; ++u) {
                    float2 w = *(const float2*)(Wr[u] + k);
                    accv[u]  += w.x * av.x  + w.y * av.y;
                    accd[u]  += w.x * ad.x  + w.y * ad.y;
                    accdd[u] += w.x * add.x + w.y * add.y;
                }
            }
        }

#pragma unroll
        for (int u = 0; u < UO; ++u) {
            int o = olist[u];
            if (o < FOUT) {
                float zv  = accv[u] + bias[o];   // bias only on the value state
                float zd  = accd[u];
                float zdd = accdd[u];
                float ov, od, odd;
                if constexpr (TANH) {
                    float t  = fast_tanh(zv);
                    float s2 = 1.0f - t * t;
                    ov  = t;
                    od  = s2 * zd;
                    odd = s2 * zdd - 2.0f * t * s2 * zd * zd;
                } else {
                    ov = zv; od = zd; odd = zdd;
                }
                ldsOut[(0 * B + s) * FOUTP + o] = ov;
                ldsOut[(1 * B + s) * FOUTP + o] = od;
                ldsOut[(2 * B + s) * FOUTP + o] = odd;
            }
        }
    }
}

__global__ __launch_bounds__(BLOCK, 2) void pinn_kernel(
    const float* __restrict__ W0, const float* __restrict__ b0,
    const float* __restrict__ W1, const float* __restrict__ b1,
    const float* __restrict__ W2, const float* __restrict__ b2,
    const float* __restrict__ W3, const float* __restrict__ b3,
    const float* __restrict__ W4, const float* __restrict__ b4,
    const float* __restrict__ W5, const float* __restrict__ b5,
    const float* __restrict__ x,  const float* __restrict__ A,
    const float* __restrict__ bvec, float* __restrict__ out)
{
    __shared__ float R0[3 * B * 204];   // 19584 B  (widths <= 200, stride 204)
    __shared__ float R1[3 * B * 504];   // 48384 B  (widths <= 500, stride 504)
    __shared__ float xs[B];
    __shared__ float Fm[B * Q];
    __shared__ float Um[B * Q];
    // total ~74.4 KB -> 2 blocks/CU

    const int tid = threadIdx.x;
    const int bid = blockIdx.x;
    const int s   = tid % B;
    const int og  = tid / B;

    // ---- Layer 0 (1 -> 20), input h=x, h'=1, h''=0 ----
    if (tid < B * 20) {
        int s0 = tid % B;
        int o  = tid / B;
        float xv = x[bid * B + s0];
        if (o == 0) xs[s0] = xv;
        float w  = W0[o];
        float t  = fast_tanh(w * xv + b0[o]);
        float s2 = 1.0f - t * t;
        R0[(0 * B + s0) * 24 + o] = t;
        R0[(1 * B + s0) * 24 + o] = s2 * w;
        R0[(2 * B + s0) * 24 + o] = -2.0f * t * s2 * w * w;
    }
    __syncthreads();

    layer<20, 24, 50, 54, true, 2, 4>(W1, b1, R0, R1, s, og);   // 20 -> 50
    __syncthreads();
    layer<50, 54, 200, 204, true, 7, 2>(W2, b2, R1, R0, s, og); // 50 -> 200
    __syncthreads();
    layer<200, 204, 500, 504, true, 8, 4>(W3, b3, R0, R1, s, og); // 200 -> 500
    __syncthreads();
    layer<500, 504, 200, 204, true, 7, 4>(W4, b4, R1, R0, s, og); // 500 -> 200
    __syncthreads();
    layer<200, 204, 100, 104, false, 4, 4>(W5, b5, R0, R1, s, og); // 200 -> 100 linear
    __syncthreads();

    // ---- Output transform: U, Uxx, F ----
    {
        int qc = tid % 32;
        int ss = tid / 32;          // 0..7
        float xv = xs[ss];
        float xm = xv * xv - 1.0f;
#pragma unroll
        for (int u = 0; u < 4; ++u) {
            int q = qc + 32 * u;
            if (q < Q) {
                float gv  = R1[(0 * B + ss) * 104 + q];
                float gd  = R1[(1 * B + ss) * 104 + q];
                float gdd = R1[(2 * B + ss) * 104 + q];
                float U   = -1.0f + xm * gv;
                float Uxx = 2.0f * gv + 4.0f * xv * gd + xm * gdd;
                float Fv  = 5.0f * U * U * U - 5.0f * U - 0.0005f * Uxx;
                Fm[ss * Q + q] = Fv;
                Um[ss * Q + q] = U;
            }
        }
    }
    __syncthreads();

    // ---- U0 = U + DT * F @ A^T ; U1 = U0 - DT * (F @ bvec^T) ----
    {
        int qc = tid % 32;
        int ss = tid / 32;
        float acc[4] = {0.f, 0.f, 0.f, 0.f};
        float cb = 0.f;
        const float* Fr = Fm + ss * Q;
#pragma unroll 5
        for (int j = 0; j < Q; j += 4) {
            float4 f4  = *(const float4*)(Fr + j);
            float4 bv4 = *(const float4*)(bvec + j);   // wave-uniform -> s_load
            cb += f4.x * bv4.x + f4.y * bv4.y + f4.z * bv4.z + f4.w * bv4.w;
#pragma unroll
            for (int u = 0; u < 4; ++u) {
                int q   = qc + 32 * u;
                int qcl = q < Q ? q : Q - 1;
                float4 a4 = *(const float4*)(A + qcl * Q + j);
                acc[u] += f4.x * a4.x + f4.y * a4.y + f4.z * a4.z + f4.w * a4.w;
            }
        }
        int sg = bid * B + ss;
#pragma unroll
        for (int u = 0; u < 4; ++u) {
            int q = qc + 32 * u;
            if (q < Q) {
                float U0 = Um[ss * Q + q] + DTC * acc[u];
                float U1 = U0 - DTC * cb;
                out[sg * Q + q] = U0;                    // U0 block (N,Q)
                out[NSAMP * Q + sg * Q + q] = U1;        // U1 block (N,Q)
            }
        }
    }
}

extern "C" void kernel_launch(void* const* d_in, const int* in_sizes, int n_in,
                              void* d_out, int out_size, void* d_ws, size_t ws_size,
                              hipStream_t stream) {
    const float* W0 = (const float*)d_in[0];
    const float* b0 = (const float*)d_in[1];
    const float* W1 = (const float*)d_in[2];
    const float* b1 = (const float*)d_in[3];
    const float* W2 = (const float*)d_in[4];
    const float* b2 = (const float*)d_in[5];
    const float* W3 = (const float*)d_in[6];
    const float* b3 = (const float*)d_in[7];
    const float* W4 = (const float*)d_in[8];
    const float* b4 = (const float*)d_in[9];
    const float* W5 = (const float*)d_in[10];
    const float* b5 = (const float*)d_in[11];
    const float* x  = (const float*)d_in[12];
    const float* A  = (const float*)d_in[13];
    const float* bv = (const float*)d_in[14];
    float* out = (float*)d_out;

    pinn_kernel<<<NSAMP / B, BLOCK, 0, stream>>>(
        W0, b0, W1, b1, W2, b2, W3, b3, W4, b4, W5, b5, x, A, bv, out);
}

// Round 3
// 773.685 us; speedup vs baseline: 3.1232x; 3.1232x over previous
//
#include <hip/hip_runtime.h>
#include <hip/hip_bf16.h>

// PINN fused forward+jvp^2 via split-fp16 MFMA.
// Layers [1,20,50,200,500,200,100]; per block: 16 samples x 3 Taylor states
// = 48 GEMM columns = 3 N-tiles of mfma_f32_16x16x32_f16.
// Precision: every operand split into fp16 hi+lo; Z = Ahi*Bhi + Ahi*Blo + Alo*Bhi
// (fp16 products exact in fp32 accum) -> ~2^-22 per-product error.

#define NSAMP 65536
#define Q     100
#define DTC   0.8f
#define BS    16
#define THREADS 512

typedef _Float16 h8 __attribute__((ext_vector_type(8)));
typedef _Float16 h4 __attribute__((ext_vector_type(4)));
typedef float    f4 __attribute__((ext_vector_type(4)));

// ---- padded weight-plane geometry (halves), Mp = max(ceil16(FOUT), Kp_next) ----
#define S1 (64*32)
#define S2 (224*64)
#define S3 (512*224)
#define S4 (224*512)
#define S5 (112*224)
#define SW (S1+S2+S3+S4+S5)      // 270848 halves per plane
#define C1 0
#define C2 (C1+S1)
#define C3 (C2+S2)
#define C4 (C3+S3)
#define C5 (C4+S4)
// padded biases (floats): Mp per layer = 64,224,512,224,112
#define BP1 0
#define BP2 64
#define BP3 288
#define BP4 800
#define BP5 1024
#define BPTOT 1136
#define WS_BIAS_BYTE_OFF (SW*2*2)   // hi+lo planes, 2 B each
// ws bytes needed: 270848*4 + 1136*4 = 1,087,936

__device__ __forceinline__ float fast_tanh(float z) {
    float az = fabsf(z);
    float e  = __expf(-2.0f * az);
    float r  = __builtin_amdgcn_rcpf(1.0f + e);
    float t  = (1.0f - e) * r;
    return copysignf(t, z);
}

struct Split { _Float16 hi, lo; };
__device__ __forceinline__ Split split16(float v) {
    Split s;
    s.hi = (_Float16)v;
    s.lo = (_Float16)(v - (float)s.hi);
    return s;
}

// ---------------- pre-pass: split/pad weights + biases into d_ws ----------------
__global__ __launch_bounds__(256) void prepass(
    const float* __restrict__ W1, const float* __restrict__ b1,
    const float* __restrict__ W2, const float* __restrict__ b2,
    const float* __restrict__ W3, const float* __restrict__ b3,
    const float* __restrict__ W4, const float* __restrict__ b4,
    const float* __restrict__ W5, const float* __restrict__ b5,
    _Float16* __restrict__ whi, float* __restrict__ biasP)
{
    int idx = blockIdx.x * 256 + threadIdx.x;
    _Float16* wlo = whi + SW;
    if (idx < SW) {
        int base, Kp, K, FOUT; const float* W;
        if      (idx < C2) { base=C1; Kp=32;  K=20;  FOUT=50;  W=W1; }
        else if (idx < C3) { base=C2; Kp=64;  K=50;  FOUT=200; W=W2; }
        else if (idx < C4) { base=C3; Kp=224; K=200; FOUT=500; W=W3; }
        else if (idx < C5) { base=C4; Kp=512; K=500; FOUT=200; W=W4; }
        else               { base=C5; Kp=224; K=200; FOUT=100; W=W5; }
        int r = idx - base;
        int o = r / Kp;
        int k = r - o * Kp;
        float v = (o < FOUT && k < K) ? W[o * K + k] : 0.f;
        Split sp = split16(v);
        whi[idx] = sp.hi; wlo[idx] = sp.lo;
    } else if (idx < SW + BPTOT) {
        int b = idx - SW;
        const float* src; int FOUT; int o;
        if      (b < BP2)  { src=b1; FOUT=50;  o=b;        }
        else if (b < BP3)  { src=b2; FOUT=200; o=b-BP2;    }
        else if (b < BP4)  { src=b3; FOUT=500; o=b-BP3;    }
        else if (b < BP5)  { src=b4; FOUT=200; o=b-BP4;    }
        else               { src=b5; FOUT=100; o=b-BP5;    }
        biasP[b] = (o < FOUT) ? src[o] : 0.f;
    }
}

// ---------------- one MFMA layer (K-loop + tanh-jvp epilogue) ----------------
// ACT planes column-major: col c in [0,48), entry k at c*STRIDE + k (halves).
// cols: state*16 + sample. B-frag: lane l -> col=l&15 (+nt*16), k0=(l>>4)*8.
// A-frag from global W plane (row-major, row stride KP): lane l -> row=mt*16+(l&15).
// C/D: col(lane&15)=sample, row((lane>>4)*4+reg)=output neuron.
template<int KP, int MTILES, int NMT, int FOUT, int SIN, int SOUT, bool TANH>
__device__ __forceinline__ void layer_mfma(
    const _Float16* __restrict__ Whi, const _Float16* __restrict__ Wlo,
    const float* __restrict__ biasP,
    _Float16* ACThi, _Float16* ACTlo, int lane, int wv)
{
    constexpr int KT = KP / 32;
    const int colS = lane & 15;
    const int kg   = lane >> 4;

    f4 acc[NMT][3];
#pragma unroll
    for (int i = 0; i < NMT; ++i)
#pragma unroll
        for (int nt = 0; nt < 3; ++nt)
            acc[i][nt] = (f4){0.f, 0.f, 0.f, 0.f};

    const int boff0 = (0 * 16 + colS) * SIN + kg * 8;
    const int boff1 = (1 * 16 + colS) * SIN + kg * 8;
    const int boff2 = (2 * 16 + colS) * SIN + kg * 8;

    const _Float16* wbh[NMT];
    const _Float16* wbl[NMT];
#pragma unroll
    for (int i = 0; i < NMT; ++i) {
        int mt  = wv + 8 * i;
        int mtc = mt < MTILES ? mt : MTILES - 1;
        int row = mtc * 16 + colS;
        wbh[i] = Whi + row * KP + kg * 8;
        wbl[i] = Wlo + row * KP + kg * 8;
    }

    for (int kt = 0; kt < KT; ++kt) {
        const int kb = kt * 32;
        h8 Bh0 = *(const h8*)(ACThi + boff0 + kb);
        h8 Bh1 = *(const h8*)(ACThi + boff1 + kb);
        h8 Bh2 = *(const h8*)(ACThi + boff2 + kb);
        h8 Bl0 = *(const h8*)(ACTlo + boff0 + kb);
        h8 Bl1 = *(const h8*)(ACTlo + boff1 + kb);
        h8 Bl2 = *(const h8*)(ACTlo + boff2 + kb);
#pragma unroll
        for (int i = 0; i < NMT; ++i) {
            h8 Ahi = *(const h8*)(wbh[i] + kb);
            h8 Alo = *(const h8*)(wbl[i] + kb);
            acc[i][0] = __builtin_amdgcn_mfma_f32_16x16x32_f16(Ahi, Bh0, acc[i][0], 0, 0, 0);
            acc[i][1] = __builtin_amdgcn_mfma_f32_16x16x32_f16(Ahi, Bh1, acc[i][1], 0, 0, 0);
            acc[i][2] = __builtin_amdgcn_mfma_f32_16x16x32_f16(Ahi, Bh2, acc[i][2], 0, 0, 0);
            acc[i][0] = __builtin_amdgcn_mfma_f32_16x16x32_f16(Ahi, Bl0, acc[i][0], 0, 0, 0);
            acc[i][1] = __builtin_amdgcn_mfma_f32_16x16x32_f16(Ahi, Bl1, acc[i][1], 0, 0, 0);
            acc[i][2] = __builtin_amdgcn_mfma_f32_16x16x32_f16(Ahi, Bl2, acc[i][2], 0, 0, 0);
            acc[i][0] = __builtin_amdgcn_mfma_f32_16x16x32_f16(Alo, Bh0, acc[i][0], 0, 0, 0);
            acc[i][1] = __builtin_amdgcn_mfma_f32_16x16x32_f16(Alo, Bh1, acc[i][1], 0, 0, 0);
            acc[i][2] = __builtin_amdgcn_mfma_f32_16x16x32_f16(Alo, Bh2, acc[i][2], 0, 0, 0);
        }
    }
    __syncthreads();   // all reads of ACT complete before in-place overwrite

#pragma unroll
    for (int i = 0; i < NMT; ++i) {
        int mt = wv + 8 * i;
        if (mt < MTILES) {
            int o0 = mt * 16 + kg * 4;
            f4 bi = *(const f4*)(biasP + o0);
            h4 phi[3], plo[3];
#pragma unroll
            for (int r = 0; r < 4; ++r) {
                float zv  = acc[i][0][r] + bi[r];
                float zd  = acc[i][1][r];
                float zdd = acc[i][2][r];
                float ov, od, odd;
                if constexpr (TANH) {
                    float t  = fast_tanh(zv);
                    float s2 = 1.0f - t * t;
                    ov  = t;
                    od  = s2 * zd;
                    odd = s2 * zdd - 2.0f * t * s2 * zd * zd;
                } else {
                    ov = zv; od = zd; odd = zdd;
                }
                if (o0 + r >= FOUT) { ov = 0.f; od = 0.f; odd = 0.f; }
                Split sv = split16(ov);
                Split sd = split16(od);
                Split sdd = split16(odd);
                phi[0][r] = sv.hi;  plo[0][r] = sv.lo;
                phi[1][r] = sd.hi;  plo[1][r] = sd.lo;
                phi[2][r] = sdd.hi; plo[2][r] = sdd.lo;
            }
#pragma unroll
            for (int st = 0; st < 3; ++st) {
                int off = (st * 16 + colS) * SOUT + o0;
                *(h4*)(ACThi + off) = phi[st];
                *(h4*)(ACTlo + off) = plo[st];
            }
        }
    }
    __syncthreads();
}

// ---------------- main fused kernel ----------------
__global__ __launch_bounds__(THREADS, 2) void pinn_mfma(
    const float* __restrict__ W0, const float* __restrict__ b0,
    const float* __restrict__ x,  const float* __restrict__ A,
    const float* __restrict__ bvec,
    const _Float16* __restrict__ whi, const float* __restrict__ biasP,
    float* __restrict__ out)
{
    __shared__ __align__(16) _Float16 ACThi[48 * 520];
    __shared__ __align__(16) _Float16 ACTlo[48 * 520];
    __shared__ float xs[BS];
    __shared__ float Fm[BS * 104];
    __shared__ float Um[BS * 104];

    const int tid  = threadIdx.x;
    const int bid  = blockIdx.x;
    const int lane = tid & 63;
    const int wv   = tid >> 6;
    const _Float16* wlo = whi + SW;

    if (tid < BS) xs[tid] = x[bid * BS + tid];
    __syncthreads();

    // ---- layer 0: 1 -> 20, write padded-K (32) L1 input, stride 40 ----
    {
        int s = tid >> 5;       // 0..15
        int k = tid & 31;       // 0..31
        float v0 = 0.f, v1 = 0.f, v2 = 0.f;
        if (tid < 512 && k < 20) {
            float w  = W0[k];
            float z  = w * xs[s] + b0[k];
            float t  = fast_tanh(z);
            float s2 = 1.0f - t * t;
            v0 = t; v1 = s2 * w; v2 = -2.0f * t * s2 * w * w;
        }
        Split s0 = split16(v0);
        Split s1 = split16(v1);
        Split s2s = split16(v2);
        ACThi[(0*16+s)*40 + k] = s0.hi;  ACTlo[(0*16+s)*40 + k] = s0.lo;
        ACThi[(1*16+s)*40 + k] = s1.hi;  ACTlo[(1*16+s)*40 + k] = s1.lo;
        ACThi[(2*16+s)*40 + k] = s2s.hi; ACTlo[(2*16+s)*40 + k] = s2s.lo;
    }
    __syncthreads();

    layer_mfma< 32,  4, 1,  50,  40,  72, true>(whi + C1, wlo + C1, biasP + BP1, ACThi, ACTlo, lane, wv);
    layer_mfma< 64, 14, 2, 200,  72, 232, true>(whi + C2, wlo + C2, biasP + BP2, ACThi, ACTlo, lane, wv);
    layer_mfma<224, 32, 4, 500, 232, 520, true>(whi + C3, wlo + C3, biasP + BP3, ACThi, ACTlo, lane, wv);
    layer_mfma<512, 14, 2, 200, 520, 232, true>(whi + C4, wlo + C4, biasP + BP4, ACThi, ACTlo, lane, wv);

    // ---- layer 5: 200 -> 100 linear, epilogue -> U, Uxx, F ----
    {
        constexpr int KP = 224, KT = 7, MTILES = 7;
        const int colS = lane & 15;
        const int kg   = lane >> 4;
        f4 acc[3];
#pragma unroll
        for (int nt = 0; nt < 3; ++nt) acc[nt] = (f4){0.f, 0.f, 0.f, 0.f};
        const int boff0 = (0*16+colS)*232 + kg*8;
        const int boff1 = (1*16+colS)*232 + kg*8;
        const int boff2 = (2*16+colS)*232 + kg*8;
        int mtc = wv < MTILES ? wv : MTILES - 1;
        const _Float16* wb5h = whi + C5 + (mtc*16 + colS)*KP + kg*8;
        const _Float16* wb5l = wlo + C5 + (mtc*16 + colS)*KP + kg*8;
        for (int kt = 0; kt < KT; ++kt) {
            const int kb = kt * 32;
            h8 Bh0 = *(const h8*)(ACThi + boff0 + kb);
            h8 Bh1 = *(const h8*)(ACThi + boff1 + kb);
            h8 Bh2 = *(const h8*)(ACThi + boff2 + kb);
            h8 Bl0 = *(const h8*)(ACTlo + boff0 + kb);
            h8 Bl1 = *(const h8*)(ACTlo + boff1 + kb);
            h8 Bl2 = *(const h8*)(ACTlo + boff2 + kb);
            h8 Ahi = *(const h8*)(wb5h + kb);
            h8 Alo = *(const h8*)(wb5l + kb);
            acc[0] = __builtin_amdgcn_mfma_f32_16x16x32_f16(Ahi, Bh0, acc[0], 0, 0, 0);
            acc[1] = __builtin_amdgcn_mfma_f32_16x16x32_f16(Ahi, Bh1, acc[1], 0, 0, 0);
            acc[2] = __builtin_amdgcn_mfma_f32_16x16x32_f16(Ahi, Bh2, acc[2], 0, 0, 0);
            acc[0] = __builtin_amdgcn_mfma_f32_16x16x32_f16(Ahi, Bl0, acc[0], 0, 0, 0);
            acc[1] = __builtin_amdgcn_mfma_f32_16x16x32_f16(Ahi, Bl1, acc[1], 0, 0, 0);
            acc[2] = __builtin_amdgcn_mfma_f32_16x16x32_f16(Ahi, Bl2, acc[2], 0, 0, 0);
            acc[0] = __builtin_amdgcn_mfma_f32_16x16x32_f16(Alo, Bh0, acc[0], 0, 0, 0);
            acc[1] = __builtin_amdgcn_mfma_f32_16x16x32_f16(Alo, Bh1, acc[1], 0, 0, 0);
            acc[2] = __builtin_amdgcn_mfma_f32_16x16x32_f16(Alo, Bh2, acc[2], 0, 0, 0);
        }
        __syncthreads();
        if (wv < MTILES) {
            int o0 = wv * 16 + kg * 4;
            f4 bi = *(const f4*)(biasP + BP5 + o0);
            float xv = xs[colS];
            float xm = xv * xv - 1.0f;
#pragma unroll
            for (int r = 0; r < 4; ++r) {
                int q = o0 + r;
                if (q < Q) {
                    float gv  = acc[0][r] + bi[r];
                    float gd  = acc[1][r];
                    float gdd = acc[2][r];
                    float U   = -1.0f + xm * gv;
                    float Uxx = 2.0f * gv + 4.0f * xv * gd + xm * gdd;
                    float Fv  = 5.0f * U * U * U - 5.0f * U - 0.0005f * Uxx;
                    Fm[colS * 104 + q] = Fv;
                    Um[colS * 104 + q] = U;
                }
            }
        }
        __syncthreads();
    }

    // ---- tail: U0 = U + DT*F@A^T ; U1 = U0 - DT*(F@bvec^T) (fp32 vector) ----
    {
        int qc = tid & 31;
        int ss = tid >> 5;
        float accq[4] = {0.f, 0.f, 0.f, 0.f};
        float cb = 0.f;
        const float* Fr = Fm + ss * 104;
#pragma unroll 5
        for (int j = 0; j < Q; j += 4) {
            f4 f4v = *(const f4*)(Fr + j);
            f4 bv4 = *(const f4*)(bvec + j);
            cb += f4v[0]*bv4[0] + f4v[1]*bv4[1] + f4v[2]*bv4[2] + f4v[3]*bv4[3];
#pragma unroll
            for (int u = 0; u < 4; ++u) {
                int q   = qc + 32 * u;
                int qcl = q < Q ? q : Q - 1;
                f4 a4 = *(const f4*)(A + qcl * Q + j);
                accq[u] += f4v[0]*a4[0] + f4v[1]*a4[1] + f4v[2]*a4[2] + f4v[3]*a4[3];
            }
        }
        int sg = bid * BS + ss;
#pragma unroll
        for (int u = 0; u < 4; ++u) {
            int q = qc + 32 * u;
            if (q < Q) {
                float U0 = Um[ss * 104 + q] + DTC * accq[u];
                float U1 = U0 - DTC * cb;
                out[sg * Q + q] = U0;
                out[NSAMP * Q + sg * Q + q] = U1;
            }
        }
    }
}

extern "C" void kernel_launch(void* const* d_in, const int* in_sizes, int n_in,
                              void* d_out, int out_size, void* d_ws, size_t ws_size,
                              hipStream_t stream) {
    const float* W0 = (const float*)d_in[0];
    const float* b0 = (const float*)d_in[1];
    const float* W1 = (const float*)d_in[2];
    const float* b1 = (const float*)d_in[3];
    const float* W2 = (const float*)d_in[4];
    const float* b2 = (const float*)d_in[5];
    const float* W3 = (const float*)d_in[6];
    const float* b3 = (const float*)d_in[7];
    const float* W4 = (const float*)d_in[8];
    const float* b4 = (const float*)d_in[9];
    const float* W5 = (const float*)d_in[10];
    const float* b5 = (const float*)d_in[11];
    const float* x  = (const float*)d_in[12];
    const float* A  = (const float*)d_in[13];
    const float* bv = (const float*)d_in[14];
    float* out = (float*)d_out;

    _Float16* whi = (_Float16*)d_ws;
    float* biasP  = (float*)((char*)d_ws + WS_BIAS_BYTE_OFF);

    prepass<<<(SW + BPTOT + 255) / 256, 256, 0, stream>>>(
        W1, b1, W2, b2, W3, b3, W4, b4, W5, b5, whi, biasP);

    pinn_mfma<<<NSAMP / BS, THREADS, 0, stream>>>(
        W0, b0, x, A, bv, whi, biasP, out);
}

// Round 4
// 745.168 us; speedup vs baseline: 3.2427x; 1.0383x over previous
//
#include <hip/hip_runtime.h>
#include <hip/hip_bf16.h>

// PINN fused forward+jvp^2 via split-fp16 MFMA.
// Layers [1,20,50,200,500,200,100]; per block: 16 samples x 3 Taylor states
// = 48 GEMM columns = 3 N-tiles of mfma_f32_16x16x32_f16.
// Precision: split into fp16 hi+lo; Z = Ahi*Bhi + Ahi*Blo + Alo*Bhi.
// R3: 1024 thr (16 waves), NMT=2 m-tiles/wave, A-prefetch dbuf, strides ==8 mod 64.

#define NSAMP 65536
#define Q     100
#define DTC   0.8f
#define BS    16
#define THREADS 1024
#define NW    16

typedef _Float16 h8 __attribute__((ext_vector_type(8)));
typedef _Float16 h4 __attribute__((ext_vector_type(4)));
typedef float    f4 __attribute__((ext_vector_type(4)));

// ---- padded weight-plane geometry (halves), Mp = max(ceil16(FOUT), Kp_next) ----
#define S1 (64*32)
#define S2 (224*64)
#define S3 (512*224)
#define S4 (224*512)
#define S5 (112*224)
#define SW (S1+S2+S3+S4+S5)      // 270848 halves per plane
#define C1 0
#define C2 (C1+S1)
#define C3 (C2+S2)
#define C4 (C3+S3)
#define C5 (C4+S4)
#define BP1 0
#define BP2 64
#define BP3 288
#define BP4 800
#define BP5 1024
#define BPTOT 1136
#define WS_BIAS_BYTE_OFF (SW*2*2)

__device__ __forceinline__ float fast_tanh(float z) {
    float az = fabsf(z);
    float e  = __expf(-2.0f * az);
    float r  = __builtin_amdgcn_rcpf(1.0f + e);
    float t  = (1.0f - e) * r;
    return copysignf(t, z);
}

struct Split { _Float16 hi, lo; };
__device__ __forceinline__ Split split16(float v) {
    Split s;
    s.hi = (_Float16)v;
    s.lo = (_Float16)(v - (float)s.hi);
    return s;
}

// ---------------- pre-pass: split/pad weights + biases into d_ws ----------------
__global__ __launch_bounds__(256) void prepass(
    const float* __restrict__ W1, const float* __restrict__ b1,
    const float* __restrict__ W2, const float* __restrict__ b2,
    const float* __restrict__ W3, const float* __restrict__ b3,
    const float* __restrict__ W4, const float* __restrict__ b4,
    const float* __restrict__ W5, const float* __restrict__ b5,
    _Float16* __restrict__ whi, float* __restrict__ biasP)
{
    int idx = blockIdx.x * 256 + threadIdx.x;
    _Float16* wlo = whi + SW;
    if (idx < SW) {
        int base, Kp, K, FOUT; const float* W;
        if      (idx < C2) { base=C1; Kp=32;  K=20;  FOUT=50;  W=W1; }
        else if (idx < C3) { base=C2; Kp=64;  K=50;  FOUT=200; W=W2; }
        else if (idx < C4) { base=C3; Kp=224; K=200; FOUT=500; W=W3; }
        else if (idx < C5) { base=C4; Kp=512; K=500; FOUT=200; W=W4; }
        else               { base=C5; Kp=224; K=200; FOUT=100; W=W5; }
        int r = idx - base;
        int o = r / Kp;
        int k = r - o * Kp;
        float v = (o < FOUT && k < K) ? W[o * K + k] : 0.f;
        Split sp = split16(v);
        whi[idx] = sp.hi; wlo[idx] = sp.lo;
    } else if (idx < SW + BPTOT) {
        int b = idx - SW;
        const float* src; int FOUT; int o;
        if      (b < BP2)  { src=b1; FOUT=50;  o=b;        }
        else if (b < BP3)  { src=b2; FOUT=200; o=b-BP2;    }
        else if (b < BP4)  { src=b3; FOUT=500; o=b-BP3;    }
        else if (b < BP5)  { src=b4; FOUT=200; o=b-BP4;    }
        else               { src=b5; FOUT=100; o=b-BP5;    }
        biasP[b] = (o < FOUT) ? src[o] : 0.f;
    }
}

// ---------------- one MFMA layer ----------------
// Active waves: wv < NWACT, each owns NMT m-tiles: mt = wv + NWACT*i.
// B-frag (LDS): lane l -> col = (l&15) + nt*16, k0 = (l>>4)*8 + kt*32.
// A-frag (global W plane, row-major stride KP): lane l -> row = mt*16+(l&15).
// C/D: col(lane&15)=sample, row((lane>>4)*4+reg)=output neuron.
template<int KP, int MTILES, int NMT, int NWACT, int FOUT, int SIN, int SOUT, bool TANH>
__device__ __forceinline__ void layer_mfma(
    const _Float16* __restrict__ Whi, const _Float16* __restrict__ Wlo,
    const float* __restrict__ biasP,
    _Float16* ACThi, _Float16* ACTlo, int lane, int wv)
{
    constexpr int KT = KP / 32;
    const int colS = lane & 15;
    const int kg   = lane >> 4;
    const bool act = (wv < NWACT);

    f4 acc[NMT][3];

    if (act) {
#pragma unroll
        for (int i = 0; i < NMT; ++i)
#pragma unroll
            for (int nt = 0; nt < 3; ++nt)
                acc[i][nt] = (f4){0.f, 0.f, 0.f, 0.f};

        const int boff0 = (0 * 16 + colS) * SIN + kg * 8;
        const int boff1 = (1 * 16 + colS) * SIN + kg * 8;
        const int boff2 = (2 * 16 + colS) * SIN + kg * 8;

        const _Float16* wbh[NMT];
        const _Float16* wbl[NMT];
#pragma unroll
        for (int i = 0; i < NMT; ++i) {
            int mt  = wv + NWACT * i;
            int mtc = mt < MTILES ? mt : MTILES - 1;
            int row = mtc * 16 + colS;
            wbh[i] = Whi + row * KP + kg * 8;
            wbl[i] = Wlo + row * KP + kg * 8;
        }

        // A double-buffer prefetch across the unrolled K loop
        h8 Ah[2][NMT], Al[2][NMT];
#pragma unroll
        for (int i = 0; i < NMT; ++i) {
            Ah[0][i] = *(const h8*)(wbh[i]);
            Al[0][i] = *(const h8*)(wbl[i]);
        }

#pragma unroll
        for (int kt = 0; kt < KT; ++kt) {
            const int cur = kt & 1;
            const int nxt = cur ^ 1;
            if (kt + 1 < KT) {
                const int kb = (kt + 1) * 32;
#pragma unroll
                for (int i = 0; i < NMT; ++i) {
                    Ah[nxt][i] = *(const h8*)(wbh[i] + kb);
                    Al[nxt][i] = *(const h8*)(wbl[i] + kb);
                }
            }
            const int kb = kt * 32;
            h8 Bh0 = *(const h8*)(ACThi + boff0 + kb);
            h8 Bh1 = *(const h8*)(ACThi + boff1 + kb);
            h8 Bh2 = *(const h8*)(ACThi + boff2 + kb);
            h8 Bl0 = *(const h8*)(ACTlo + boff0 + kb);
            h8 Bl1 = *(const h8*)(ACTlo + boff1 + kb);
            h8 Bl2 = *(const h8*)(ACTlo + boff2 + kb);
#pragma unroll
            for (int i = 0; i < NMT; ++i) {
                if (wv + NWACT * i < MTILES) {
                    h8 Ahi = Ah[cur][i];
                    h8 Alo = Al[cur][i];
                    acc[i][0] = __builtin_amdgcn_mfma_f32_16x16x32_f16(Ahi, Bh0, acc[i][0], 0, 0, 0);
                    acc[i][1] = __builtin_amdgcn_mfma_f32_16x16x32_f16(Ahi, Bh1, acc[i][1], 0, 0, 0);
                    acc[i][2] = __builtin_amdgcn_mfma_f32_16x16x32_f16(Ahi, Bh2, acc[i][2], 0, 0, 0);
                    acc[i][0] = __builtin_amdgcn_mfma_f32_16x16x32_f16(Ahi, Bl0, acc[i][0], 0, 0, 0);
                    acc[i][1] = __builtin_amdgcn_mfma_f32_16x16x32_f16(Ahi, Bl1, acc[i][1], 0, 0, 0);
                    acc[i][2] = __builtin_amdgcn_mfma_f32_16x16x32_f16(Ahi, Bl2, acc[i][2], 0, 0, 0);
                    acc[i][0] = __builtin_amdgcn_mfma_f32_16x16x32_f16(Alo, Bh0, acc[i][0], 0, 0, 0);
                    acc[i][1] = __builtin_amdgcn_mfma_f32_16x16x32_f16(Alo, Bh1, acc[i][1], 0, 0, 0);
                    acc[i][2] = __builtin_amdgcn_mfma_f32_16x16x32_f16(Alo, Bh2, acc[i][2], 0, 0, 0);
                }
            }
        }
    }
    __syncthreads();   // all reads of ACT complete before in-place overwrite

    if (act) {
#pragma unroll
        for (int i = 0; i < NMT; ++i) {
            int mt = wv + NWACT * i;
            if (mt < MTILES) {
                int o0 = mt * 16 + kg * 4;
                f4 bi = *(const f4*)(biasP + o0);
                h4 phi[3], plo[3];
#pragma unroll
                for (int r = 0; r < 4; ++r) {
                    float zv  = acc[i][0][r] + bi[r];
                    float zd  = acc[i][1][r];
                    float zdd = acc[i][2][r];
                    float ov, od, odd;
                    if constexpr (TANH) {
                        float t  = fast_tanh(zv);
                        float s2 = 1.0f - t * t;
                        ov  = t;
                        od  = s2 * zd;
                        odd = s2 * zdd - 2.0f * t * s2 * zd * zd;
                    } else {
                        ov = zv; od = zd; odd = zdd;
                    }
                    if (o0 + r >= FOUT) { ov = 0.f; od = 0.f; odd = 0.f; }
                    Split sv  = split16(ov);
                    Split sd  = split16(od);
                    Split sdd = split16(odd);
                    phi[0][r] = sv.hi;  plo[0][r] = sv.lo;
                    phi[1][r] = sd.hi;  plo[1][r] = sd.lo;
                    phi[2][r] = sdd.hi; plo[2][r] = sdd.lo;
                }
#pragma unroll
                for (int st = 0; st < 3; ++st) {
                    int off = (st * 16 + colS) * SOUT + o0;
                    *(h4*)(ACThi + off) = phi[st];
                    *(h4*)(ACTlo + off) = plo[st];
                }
            }
        }
    }
    __syncthreads();
}

// ---------------- main fused kernel ----------------
__global__ __launch_bounds__(THREADS, 4) void pinn_mfma(
    const float* __restrict__ W0, const float* __restrict__ b0,
    const float* __restrict__ x,  const float* __restrict__ A,
    const float* __restrict__ bvec,
    const _Float16* __restrict__ whi, const float* __restrict__ biasP,
    float* __restrict__ out)
{
    __shared__ __align__(16) _Float16 ACThi[48 * 520];
    __shared__ __align__(16) _Float16 ACTlo[48 * 520];
    __shared__ float xs[BS];
    __shared__ float Fm[BS * 104];
    __shared__ float Um[BS * 104];

    const int tid  = threadIdx.x;
    const int bid  = blockIdx.x;
    const int lane = tid & 63;
    const int wv   = tid >> 6;
    const _Float16* wlo = whi + SW;

    if (tid < BS) xs[tid] = x[bid * BS + tid];
    __syncthreads();

    // ---- layer 0: 1 -> 20, write padded-K (32) L1 input, stride 72 ----
    if (tid < 512) {
        int s = tid >> 5;       // 0..15
        int k = tid & 31;       // 0..31
        float v0 = 0.f, v1 = 0.f, v2 = 0.f;
        if (k < 20) {
            float w  = W0[k];
            float z  = w * xs[s] + b0[k];
            float t  = fast_tanh(z);
            float s2 = 1.0f - t * t;
            v0 = t; v1 = s2 * w; v2 = -2.0f * t * s2 * w * w;
        }
        Split s0  = split16(v0);
        Split s1  = split16(v1);
        Split s2s = split16(v2);
        ACThi[(0*16+s)*72 + k] = s0.hi;  ACTlo[(0*16+s)*72 + k] = s0.lo;
        ACThi[(1*16+s)*72 + k] = s1.hi;  ACTlo[(1*16+s)*72 + k] = s1.lo;
        ACThi[(2*16+s)*72 + k] = s2s.hi; ACTlo[(2*16+s)*72 + k] = s2s.lo;
    }
    __syncthreads();

    //            KP  MT NMT NWA FOUT SIN  SOUT
    layer_mfma<  32,  4, 1,  4,  50,  72,  72, true>(whi + C1, wlo + C1, biasP + BP1, ACThi, ACTlo, lane, wv);
    layer_mfma<  64, 14, 2,  7, 200,  72, 264, true>(whi + C2, wlo + C2, biasP + BP2, ACThi, ACTlo, lane, wv);
    layer_mfma< 224, 32, 2, 16, 500, 264, 520, true>(whi + C3, wlo + C3, biasP + BP3, ACThi, ACTlo, lane, wv);
    layer_mfma< 512, 14, 2,  7, 200, 520, 264, true>(whi + C4, wlo + C4, biasP + BP4, ACThi, ACTlo, lane, wv);

    // ---- layer 5: 200 -> 100 linear (NMT=2, waves 0..3), epilogue -> U, Uxx, F ----
    {
        constexpr int KP = 224, KT = 7, MTILES = 7, NWACT = 4;
        const int colS = lane & 15;
        const int kg   = lane >> 4;
        const bool act = (wv < NWACT);
        f4 acc[2][3];
        if (act) {
#pragma unroll
            for (int i = 0; i < 2; ++i)
#pragma unroll
                for (int nt = 0; nt < 3; ++nt) acc[i][nt] = (f4){0.f, 0.f, 0.f, 0.f};
            const int boff0 = (0*16+colS)*264 + kg*8;
            const int boff1 = (1*16+colS)*264 + kg*8;
            const int boff2 = (2*16+colS)*264 + kg*8;
            const _Float16* wbh[2];
            const _Float16* wbl[2];
#pragma unroll
            for (int i = 0; i < 2; ++i) {
                int mt  = wv + NWACT * i;
                int mtc = mt < MTILES ? mt : MTILES - 1;
                wbh[i] = whi + C5 + (mtc*16 + colS)*KP + kg*8;
                wbl[i] = wlo + C5 + (mtc*16 + colS)*KP + kg*8;
            }
            h8 Ah[2][2], Al[2][2];
#pragma unroll
            for (int i = 0; i < 2; ++i) {
                Ah[0][i] = *(const h8*)(wbh[i]);
                Al[0][i] = *(const h8*)(wbl[i]);
            }
#pragma unroll
            for (int kt = 0; kt < KT; ++kt) {
                const int cur = kt & 1, nxt = cur ^ 1;
                if (kt + 1 < KT) {
                    const int kb = (kt + 1) * 32;
#pragma unroll
                    for (int i = 0; i < 2; ++i) {
                        Ah[nxt][i] = *(const h8*)(wbh[i] + kb);
                        Al[nxt][i] = *(const h8*)(wbl[i] + kb);
                    }
                }
                const int kb = kt * 32;
                h8 Bh0 = *(const h8*)(ACThi + boff0 + kb);
                h8 Bh1 = *(const h8*)(ACThi + boff1 + kb);
                h8 Bh2 = *(const h8*)(ACThi + boff2 + kb);
                h8 Bl0 = *(const h8*)(ACTlo + boff0 + kb);
                h8 Bl1 = *(const h8*)(ACTlo + boff1 + kb);
                h8 Bl2 = *(const h8*)(ACTlo + boff2 + kb);
#pragma unroll
                for (int i = 0; i < 2; ++i) {
                    if (wv + NWACT * i < MTILES) {
                        h8 Ahi = Ah[cur][i];
                        h8 Alo = Al[cur][i];
                        acc[i][0] = __builtin_amdgcn_mfma_f32_16x16x32_f16(Ahi, Bh0, acc[i][0], 0, 0, 0);
                        acc[i][1] = __builtin_amdgcn_mfma_f32_16x16x32_f16(Ahi, Bh1, acc[i][1], 0, 0, 0);
                        acc[i][2] = __builtin_amdgcn_mfma_f32_16x16x32_f16(Ahi, Bh2, acc[i][2], 0, 0, 0);
                        acc[i][0] = __builtin_amdgcn_mfma_f32_16x16x32_f16(Ahi, Bl0, acc[i][0], 0, 0, 0);
                        acc[i][1] = __builtin_amdgcn_mfma_f32_16x16x32_f16(Ahi, Bl1, acc[i][1], 0, 0, 0);
                        acc[i][2] = __builtin_amdgcn_mfma_f32_16x16x32_f16(Ahi, Bl2, acc[i][2], 0, 0, 0);
                        acc[i][0] = __builtin_amdgcn_mfma_f32_16x16x32_f16(Alo, Bh0, acc[i][0], 0, 0, 0);
                        acc[i][1] = __builtin_amdgcn_mfma_f32_16x16x32_f16(Alo, Bh1, acc[i][1], 0, 0, 0);
                        acc[i][2] = __builtin_amdgcn_mfma_f32_16x16x32_f16(Alo, Bh2, acc[i][2], 0, 0, 0);
                    }
                }
            }
        }
        __syncthreads();
        if (act) {
#pragma unroll
            for (int i = 0; i < 2; ++i) {
                int mt = wv + NWACT * i;
                if (mt < MTILES) {
                    int o0 = mt * 16 + kg * 4;
                    f4 bi = *(const f4*)(biasP + BP5 + o0);
                    float xv = xs[colS];
                    float xm = xv * xv - 1.0f;
#pragma unroll
                    for (int r = 0; r < 4; ++r) {
                        int q = o0 + r;
                        if (q < Q) {
                            float gv  = acc[i][0][r] + bi[r];
                            float gd  = acc[i][1][r];
                            float gdd = acc[i][2][r];
                            float U   = -1.0f + xm * gv;
                            float Uxx = 2.0f * gv + 4.0f * xv * gd + xm * gdd;
                            float Fv  = 5.0f * U * U * U - 5.0f * U - 0.0005f * Uxx;
                            Fm[colS * 104 + q] = Fv;
                            Um[colS * 104 + q] = U;
                        }
                    }
                }
            }
        }
        __syncthreads();
    }

    // ---- tail: U0 = U + DT*F@A^T ; U1 = U0 - DT*(F@bvec^T) (fp32 vector) ----
    {
        int qc = tid & 63;          // candidate q (and q+64)
        int ss = tid >> 6;          // sample 0..15
        float accq[2] = {0.f, 0.f};
        float cb = 0.f;
        const float* Fr = Fm + ss * 104;
#pragma unroll 5
        for (int j = 0; j < Q; j += 4) {
            f4 f4v = *(const f4*)(Fr + j);
            f4 bv4 = *(const f4*)(bvec + j);
            cb += f4v[0]*bv4[0] + f4v[1]*bv4[1] + f4v[2]*bv4[2] + f4v[3]*bv4[3];
#pragma unroll
            for (int u = 0; u < 2; ++u) {
                int q   = qc + 64 * u;
                int qcl = q < Q ? q : Q - 1;
                f4 a4 = *(const f4*)(A + qcl * Q + j);
                accq[u] += f4v[0]*a4[0] + f4v[1]*a4[1] + f4v[2]*a4[2] + f4v[3]*a4[3];
            }
        }
        int sg = bid * BS + ss;
#pragma unroll
        for (int u = 0; u < 2; ++u) {
            int q = qc + 64 * u;
            if (q < Q) {
                float U0 = Um[ss * 104 + q] + DTC * accq[u];
                float U1 = U0 - DTC * cb;
                out[sg * Q + q] = U0;
                out[NSAMP * Q + sg * Q + q] = U1;
            }
        }
    }
}

extern "C" void kernel_launch(void* const* d_in, const int* in_sizes, int n_in,
                              void* d_out, int out_size, void* d_ws, size_t ws_size,
                              hipStream_t stream) {
    const float* W0 = (const float*)d_in[0];
    const float* b0 = (const float*)d_in[1];
    const float* W1 = (const float*)d_in[2];
    const float* b1 = (const float*)d_in[3];
    const float* W2 = (const float*)d_in[4];
    const float* b2 = (const float*)d_in[5];
    const float* W3 = (const float*)d_in[6];
    const float* b3 = (const float*)d_in[7];
    const float* W4 = (const float*)d_in[8];
    const float* b4 = (const float*)d_in[9];
    const float* W5 = (const float*)d_in[10];
    const float* b5 = (const float*)d_in[11];
    const float* x  = (const float*)d_in[12];
    const float* A  = (const float*)d_in[13];
    const float* bv = (const float*)d_in[14];
    float* out = (float*)d_out;

    _Float16* whi = (_Float16*)d_ws;
    float* biasP  = (float*)((char*)d_ws + WS_BIAS_BYTE_OFF);

    prepass<<<(SW + BPTOT + 255) / 256, 256, 0, stream>>>(
        W1, b1, W2, b2, W3, b3, W4, b4, W5, b5, whi, biasP);

    pinn_mfma<<<NSAMP / BS, THREADS, 0, stream>>>(
        W0, b0, x, A, bv, whi, biasP, out);
}

// Round 5
// 696.469 us; speedup vs baseline: 3.4695x; 1.0699x over previous
//
#include <hip/hip_runtime.h>
#include <hip/hip_bf16.h>

// PINN fused forward+jvp^2 via split-fp16 MFMA.
// R5: v-state = 3-product split-fp16; d/dd states = plain fp16 (outputs depend
// on them only via 0.0005*Uxx -> sensitivity ~4e-5). 4 LDS planes (vhi,vlo,dhi,ddhi)
// ~67 KB -> 2 blocks/CU = 32 waves/CU. M-tiles spread over all 16 waves.

#define NSAMP 65536
#define Q     100
#define DTC   0.8f
#define BS    16
#define THREADS 1024
#define STR   520          // uniform plane stride (halves); fits KP<=512

typedef _Float16 h8 __attribute__((ext_vector_type(8)));
typedef _Float16 h4 __attribute__((ext_vector_type(4)));
typedef float    f4 __attribute__((ext_vector_type(4)));

// ---- padded weight-plane geometry (halves), Mp = max(ceil16(FOUT), Kp_next) ----
#define S1 (64*32)
#define S2 (224*64)
#define S3 (512*224)
#define S4 (224*512)
#define S5 (112*224)
#define SW (S1+S2+S3+S4+S5)      // 270848 halves per plane
#define C1 0
#define C2 (C1+S1)
#define C3 (C2+S2)
#define C4 (C3+S3)
#define C5 (C4+S4)
#define BP1 0
#define BP2 64
#define BP3 288
#define BP4 800
#define BP5 1024
#define BPTOT 1136
#define WS_BIAS_BYTE_OFF (SW*2*2)

__device__ __forceinline__ float fast_tanh(float z) {
    float az = fabsf(z);
    float e  = __expf(-2.0f * az);
    float r  = __builtin_amdgcn_rcpf(1.0f + e);
    float t  = (1.0f - e) * r;
    return copysignf(t, z);
}

struct Split { _Float16 hi, lo; };
__device__ __forceinline__ Split split16(float v) {
    Split s;
    s.hi = (_Float16)v;
    s.lo = (_Float16)(v - (float)s.hi);
    return s;
}

// ---------------- pre-pass: split/pad weights + biases into d_ws ----------------
__global__ __launch_bounds__(256) void prepass(
    const float* __restrict__ W1, const float* __restrict__ b1,
    const float* __restrict__ W2, const float* __restrict__ b2,
    const float* __restrict__ W3, const float* __restrict__ b3,
    const float* __restrict__ W4, const float* __restrict__ b4,
    const float* __restrict__ W5, const float* __restrict__ b5,
    _Float16* __restrict__ whi, float* __restrict__ biasP)
{
    int idx = blockIdx.x * 256 + threadIdx.x;
    _Float16* wlo = whi + SW;
    if (idx < SW) {
        int base, Kp, K, FOUT; const float* W;
        if      (idx < C2) { base=C1; Kp=32;  K=20;  FOUT=50;  W=W1; }
        else if (idx < C3) { base=C2; Kp=64;  K=50;  FOUT=200; W=W2; }
        else if (idx < C4) { base=C3; Kp=224; K=200; FOUT=500; W=W3; }
        else if (idx < C5) { base=C4; Kp=512; K=500; FOUT=200; W=W4; }
        else               { base=C5; Kp=224; K=200; FOUT=100; W=W5; }
        int r = idx - base;
        int o = r / Kp;
        int k = r - o * Kp;
        float v = (o < FOUT && k < K) ? W[o * K + k] : 0.f;
        Split sp = split16(v);
        whi[idx] = sp.hi; wlo[idx] = sp.lo;
    } else if (idx < SW + BPTOT) {
        int b = idx - SW;
        const float* src; int FOUT; int o;
        if      (b < BP2)  { src=b1; FOUT=50;  o=b;        }
        else if (b < BP3)  { src=b2; FOUT=200; o=b-BP2;    }
        else if (b < BP4)  { src=b3; FOUT=500; o=b-BP3;    }
        else if (b < BP5)  { src=b4; FOUT=200; o=b-BP4;    }
        else               { src=b5; FOUT=100; o=b-BP5;    }
        biasP[b] = (o < FOUT) ? src[o] : 0.f;
    }
}

// ---------------- one MFMA layer ----------------
// Planes (LDS, stride STR halves): vhi, vlo (split v-state), dhi, ddh (fp16 d/dd).
// B-frag: lane l -> col = l&15 (sample), k0 = (l>>4)*8 + kt*32.
// A-frag (global W plane, row-major stride KP): lane l -> row = mt*16+(l&15).
// C/D: col(lane&15)=sample, row((lane>>4)*4+reg)=output neuron.
// Per (kt,mt): 5 MFMAs: v: Ahi*Bvh + Ahi*Bvl + Alo*Bvh ; d: Ahi*Bdh ; dd: Ahi*Bdd.
template<int KP, int MTILES, int NMT, int NWACT, int FOUT, bool TANH>
__device__ __forceinline__ void layer_mfma(
    const _Float16* __restrict__ Whi, const _Float16* __restrict__ Wlo,
    const float* __restrict__ biasP,
    _Float16* vhi, _Float16* vlo, _Float16* dhi, _Float16* ddh,
    int lane, int wv)
{
    constexpr int KT = KP / 32;
    const int colS = lane & 15;
    const int kg   = lane >> 4;
    const bool act = (wv < NWACT);

    f4 accv[NMT], accd[NMT], accdd[NMT];

    if (act) {
#pragma unroll
        for (int i = 0; i < NMT; ++i) {
            accv[i]  = (f4){0.f, 0.f, 0.f, 0.f};
            accd[i]  = (f4){0.f, 0.f, 0.f, 0.f};
            accdd[i] = (f4){0.f, 0.f, 0.f, 0.f};
        }

        const int boff = colS * STR + kg * 8;

        const _Float16* wbh[NMT];
        const _Float16* wbl[NMT];
#pragma unroll
        for (int i = 0; i < NMT; ++i) {
            int mt  = wv + NWACT * i;
            int mtc = mt < MTILES ? mt : MTILES - 1;
            int row = mtc * 16 + colS;
            wbh[i] = Whi + row * KP + kg * 8;
            wbl[i] = Wlo + row * KP + kg * 8;
        }

        // A double-buffer prefetch across the unrolled K loop
        h8 Ah[2][NMT], Al[2][NMT];
#pragma unroll
        for (int i = 0; i < NMT; ++i) {
            Ah[0][i] = *(const h8*)(wbh[i]);
            Al[0][i] = *(const h8*)(wbl[i]);
        }

#pragma unroll
        for (int kt = 0; kt < KT; ++kt) {
            const int cur = kt & 1;
            const int nxt = cur ^ 1;
            if (kt + 1 < KT) {
                const int kb = (kt + 1) * 32;
#pragma unroll
                for (int i = 0; i < NMT; ++i) {
                    Ah[nxt][i] = *(const h8*)(wbh[i] + kb);
                    Al[nxt][i] = *(const h8*)(wbl[i] + kb);
                }
            }
            const int kb = kt * 32;
            h8 Bvh = *(const h8*)(vhi + boff + kb);
            h8 Bvl = *(const h8*)(vlo + boff + kb);
            h8 Bdh = *(const h8*)(dhi + boff + kb);
            h8 Bdd = *(const h8*)(ddh + boff + kb);
#pragma unroll
            for (int i = 0; i < NMT; ++i) {
                if (wv + NWACT * i < MTILES) {
                    h8 Ahi = Ah[cur][i];
                    h8 Alo = Al[cur][i];
                    accv[i]  = __builtin_amdgcn_mfma_f32_16x16x32_f16(Ahi, Bvh, accv[i],  0, 0, 0);
                    accv[i]  = __builtin_amdgcn_mfma_f32_16x16x32_f16(Ahi, Bvl, accv[i],  0, 0, 0);
                    accv[i]  = __builtin_amdgcn_mfma_f32_16x16x32_f16(Alo, Bvh, accv[i],  0, 0, 0);
                    accd[i]  = __builtin_amdgcn_mfma_f32_16x16x32_f16(Ahi, Bdh, accd[i],  0, 0, 0);
                    accdd[i] = __builtin_amdgcn_mfma_f32_16x16x32_f16(Ahi, Bdd, accdd[i], 0, 0, 0);
                }
            }
        }
    }
    __syncthreads();   // all reads of planes complete before in-place overwrite

    if (act) {
#pragma unroll
        for (int i = 0; i < NMT; ++i) {
            int mt = wv + NWACT * i;
            if (mt < MTILES) {
                int o0 = mt * 16 + kg * 4;
                f4 bi = *(const f4*)(biasP + o0);
                h4 pvh, pvl, pdh, pdd;
#pragma unroll
                for (int r = 0; r < 4; ++r) {
                    float zv  = accv[i][r] + bi[r];
                    float zd  = accd[i][r];
                    float zdd = accdd[i][r];
                    float ov, od, odd;
                    if constexpr (TANH) {
                        float t  = fast_tanh(zv);
                        float s2 = 1.0f - t * t;
                        ov  = t;
                        od  = s2 * zd;
                        odd = s2 * zdd - 2.0f * t * s2 * zd * zd;
                    } else {
                        ov = zv; od = zd; odd = zdd;
                    }
                    if (o0 + r >= FOUT) { ov = 0.f; od = 0.f; odd = 0.f; }
                    Split sv = split16(ov);
                    pvh[r] = sv.hi; pvl[r] = sv.lo;
                    pdh[r] = (_Float16)od;
                    pdd[r] = (_Float16)odd;
                }
                int off = colS * STR + o0;
                *(h4*)(vhi + off) = pvh;
                *(h4*)(vlo + off) = pvl;
                *(h4*)(dhi + off) = pdh;
                *(h4*)(ddh + off) = pdd;
            }
        }
    }
    __syncthreads();
}

// ---------------- main fused kernel ----------------
__global__ __launch_bounds__(THREADS, 8) void pinn_mfma(
    const float* __restrict__ W0, const float* __restrict__ b0,
    const float* __restrict__ x,  const float* __restrict__ A,
    const float* __restrict__ bvec,
    const _Float16* __restrict__ whi, const float* __restrict__ biasP,
    float* __restrict__ out)
{
    __shared__ __align__(16) _Float16 smem[4 * BS * STR];   // 66,560 B
    __shared__ float xs[BS];

    _Float16* vhi = smem + 0 * BS * STR;
    _Float16* vlo = smem + 1 * BS * STR;
    _Float16* dhi = smem + 2 * BS * STR;
    _Float16* ddh = smem + 3 * BS * STR;
    // Fm/Um overlay the plane space after the last MFMA layer's barrier
    float* Fm = (float*)smem;              // 16 x 104 floats
    float* Um = Fm + BS * 104;

    const int tid  = threadIdx.x;
    const int bid  = blockIdx.x;
    const int lane = tid & 63;
    const int wv   = tid >> 6;
    const _Float16* wlo = whi + SW;

    if (tid < BS) xs[tid] = x[bid * BS + tid];
    __syncthreads();

    // ---- layer 0: 1 -> 20, write padded-K (32) input planes ----
    if (tid < 512) {
        int s = tid >> 5;       // 0..15
        int k = tid & 31;       // 0..31
        float v0 = 0.f, v1 = 0.f, v2 = 0.f;
        if (k < 20) {
            float w  = W0[k];
            float z  = w * xs[s] + b0[k];
            float t  = fast_tanh(z);
            float s2 = 1.0f - t * t;
            v0 = t; v1 = s2 * w; v2 = -2.0f * t * s2 * w * w;
        }
        Split s0 = split16(v0);
        int off = s * STR + k;
        vhi[off] = s0.hi;           vlo[off] = s0.lo;
        dhi[off] = (_Float16)v1;    ddh[off] = (_Float16)v2;
    }
    __syncthreads();

    //          KP   MT NMT NWA FOUT
    layer_mfma< 32,  4, 1,  4,  50, true>(whi + C1, wlo + C1, biasP + BP1, vhi, vlo, dhi, ddh, lane, wv);
    layer_mfma< 64, 14, 1, 14, 200, true>(whi + C2, wlo + C2, biasP + BP2, vhi, vlo, dhi, ddh, lane, wv);
    layer_mfma<224, 32, 2, 16, 500, true>(whi + C3, wlo + C3, biasP + BP3, vhi, vlo, dhi, ddh, lane, wv);
    layer_mfma<512, 14, 1, 14, 200, true>(whi + C4, wlo + C4, biasP + BP4, vhi, vlo, dhi, ddh, lane, wv);

    // ---- layer 5: 200 -> 100 linear, epilogue -> U, Uxx, F (overlay) ----
    {
        constexpr int KP = 224, KT = 7, MTILES = 7, NWACT = 7;
        const int colS = lane & 15;
        const int kg   = lane >> 4;
        const bool act = (wv < NWACT);
        f4 av = (f4){0.f,0.f,0.f,0.f}, ad = av, add = av;
        if (act) {
            const int boff = colS * STR + kg * 8;
            const _Float16* wb5h = whi + C5 + (wv*16 + colS)*KP + kg*8;
            const _Float16* wb5l = wlo + C5 + (wv*16 + colS)*KP + kg*8;
            h8 Ah[2], Al[2];
            Ah[0] = *(const h8*)(wb5h);
            Al[0] = *(const h8*)(wb5l);
#pragma unroll
            for (int kt = 0; kt < KT; ++kt) {
                const int cur = kt & 1, nxt = cur ^ 1;
                if (kt + 1 < KT) {
                    const int kb = (kt + 1) * 32;
                    Ah[nxt] = *(const h8*)(wb5h + kb);
                    Al[nxt] = *(const h8*)(wb5l + kb);
                }
                const int kb = kt * 32;
                h8 Bvh = *(const h8*)(vhi + boff + kb);
                h8 Bvl = *(const h8*)(vlo + boff + kb);
                h8 Bdh = *(const h8*)(dhi + boff + kb);
                h8 Bdd = *(const h8*)(ddh + boff + kb);
                av  = __builtin_amdgcn_mfma_f32_16x16x32_f16(Ah[cur], Bvh, av,  0, 0, 0);
                av  = __builtin_amdgcn_mfma_f32_16x16x32_f16(Ah[cur], Bvl, av,  0, 0, 0);
                av  = __builtin_amdgcn_mfma_f32_16x16x32_f16(Al[cur], Bvh, av,  0, 0, 0);
                ad  = __builtin_amdgcn_mfma_f32_16x16x32_f16(Ah[cur], Bdh, ad,  0, 0, 0);
                add = __builtin_amdgcn_mfma_f32_16x16x32_f16(Ah[cur], Bdd, add, 0, 0, 0);
            }
        }
        __syncthreads();   // planes dead after this point; overlay Fm/Um
        if (act) {
            int o0 = wv * 16 + kg * 4;
            f4 bi = *(const f4*)(biasP + BP5 + o0);
            float xv = xs[colS];
            float xm = xv * xv - 1.0f;
#pragma unroll
            for (int r = 0; r < 4; ++r) {
                int q = o0 + r;
                if (q < Q) {
                    float gv  = av[r] + bi[r];
                    float gd  = ad[r];
                    float gdd = add[r];
                    float U   = -1.0f + xm * gv;
                    float Uxx = 2.0f * gv + 4.0f * xv * gd + xm * gdd;
                    float Fv  = 5.0f * U * U * U - 5.0f * U - 0.0005f * Uxx;
                    Fm[colS * 104 + q] = Fv;
                    Um[colS * 104 + q] = U;
                }
            }
        }
        __syncthreads();
    }

    // ---- tail: U0 = U + DT*F@A^T ; U1 = U0 - DT*(F@bvec^T) (fp32 vector) ----
    {
        int qc = tid & 63;          // candidate q (and q+64)
        int ss = tid >> 6;          // sample 0..15
        float accq[2] = {0.f, 0.f};
        float cb = 0.f;
        const float* Fr = Fm + ss * 104;
#pragma unroll 5
        for (int j = 0; j < Q; j += 4) {
            f4 f4v = *(const f4*)(Fr + j);
            f4 bv4 = *(const f4*)(bvec + j);
            cb += f4v[0]*bv4[0] + f4v[1]*bv4[1] + f4v[2]*bv4[2] + f4v[3]*bv4[3];
#pragma unroll
            for (int u = 0; u < 2; ++u) {
                int q   = qc + 64 * u;
                int qcl = q < Q ? q : Q - 1;
                f4 a4 = *(const f4*)(A + qcl * Q + j);
                accq[u] += f4v[0]*a4[0] + f4v[1]*a4[1] + f4v[2]*a4[2] + f4v[3]*a4[3];
            }
        }
        int sg = bid * BS + ss;
#pragma unroll
        for (int u = 0; u < 2; ++u) {
            int q = qc + 64 * u;
            if (q < Q) {
                float U0 = Um[ss * 104 + q] + DTC * accq[u];
                float U1 = U0 - DTC * cb;
                out[sg * Q + q] = U0;
                out[NSAMP * Q + sg * Q + q] = U1;
            }
        }
    }
}

extern "C" void kernel_launch(void* const* d_in, const int* in_sizes, int n_in,
                              void* d_out, int out_size, void* d_ws, size_t ws_size,
                              hipStream_t stream) {
    const float* W0 = (const float*)d_in[0];
    const float* b0 = (const float*)d_in[1];
    const float* W1 = (const float*)d_in[2];
    const float* b1 = (const float*)d_in[3];
    const float* W2 = (const float*)d_in[4];
    const float* b2 = (const float*)d_in[5];
    const float* W3 = (const float*)d_in[6];
    const float* b3 = (const float*)d_in[7];
    const float* W4 = (const float*)d_in[8];
    const float* b4 = (const float*)d_in[9];
    const float* W5 = (const float*)d_in[10];
    const float* b5 = (const float*)d_in[11];
    const float* x  = (const float*)d_in[12];
    const float* A  = (const float*)d_in[13];
    const float* bv = (const float*)d_in[14];
    float* out = (float*)d_out;

    _Float16* whi = (_Float16*)d_ws;
    float* biasP  = (float*)((char*)d_ws + WS_BIAS_BYTE_OFF);

    prepass<<<(SW + BPTOT + 255) / 256, 256, 0, stream>>>(
        W1, b1, W2, b2, W3, b3, W4, b4, W5, b5, whi, biasP);

    pinn_mfma<<<NSAMP / BS, THREADS, 0, stream>>>(
        W0, b0, x, A, bv, whi, biasP, out);
}

// Round 6
// 680.419 us; speedup vs baseline: 3.5513x; 1.0236x over previous
//
#include <hip/hip_runtime.h>
#include <hip/hip_bf16.h>

// PINN fused forward+jvp^2 via split-fp16 MFMA.
// R6: same structure as R5 (4 LDS planes vhi/vlo/dhi/ddh, 2 blocks/CU, 5 MFMA
// per (kt,mt)) but NO explicit A double-buffer: R5's dbuf overflowed the
// 64-VGPR cap from __launch_bounds__(1024,8) -> 170+ MB scratch spill traffic
// per dispatch (WRITE_SIZE 218 MB). Inline A loads keep peak ~56 VGPRs; 8
// waves/SIMD TLP hides the L2 latency instead.

#define NSAMP 65536
#define Q     100
#define DTC   0.8f
#define BS    16
#define THREADS 1024
#define STR   520          // uniform plane stride (halves); fits KP<=512

typedef _Float16 h8 __attribute__((ext_vector_type(8)));
typedef _Float16 h4 __attribute__((ext_vector_type(4)));
typedef float    f4 __attribute__((ext_vector_type(4)));

// ---- padded weight-plane geometry (halves), Mp = max(ceil16(FOUT), Kp_next) ----
#define S1 (64*32)
#define S2 (224*64)
#define S3 (512*224)
#define S4 (224*512)
#define S5 (112*224)
#define SW (S1+S2+S3+S4+S5)      // 270848 halves per plane
#define C1 0
#define C2 (C1+S1)
#define C3 (C2+S2)
#define C4 (C3+S3)
#define C5 (C4+S4)
#define BP1 0
#define BP2 64
#define BP3 288
#define BP4 800
#define BP5 1024
#define BPTOT 1136
#define WS_BIAS_BYTE_OFF (SW*2*2)

__device__ __forceinline__ float fast_tanh(float z) {
    float az = fabsf(z);
    float e  = __expf(-2.0f * az);
    float r  = __builtin_amdgcn_rcpf(1.0f + e);
    float t  = (1.0f - e) * r;
    return copysignf(t, z);
}

struct Split { _Float16 hi, lo; };
__device__ __forceinline__ Split split16(float v) {
    Split s;
    s.hi = (_Float16)v;
    s.lo = (_Float16)(v - (float)s.hi);
    return s;
}

// ---------------- pre-pass: split/pad weights + biases into d_ws ----------------
__global__ __launch_bounds__(256) void prepass(
    const float* __restrict__ W1, const float* __restrict__ b1,
    const float* __restrict__ W2, const float* __restrict__ b2,
    const float* __restrict__ W3, const float* __restrict__ b3,
    const float* __restrict__ W4, const float* __restrict__ b4,
    const float* __restrict__ W5, const float* __restrict__ b5,
    _Float16* __restrict__ whi, float* __restrict__ biasP)
{
    int idx = blockIdx.x * 256 + threadIdx.x;
    _Float16* wlo = whi + SW;
    if (idx < SW) {
        int base, Kp, K, FOUT; const float* W;
        if      (idx < C2) { base=C1; Kp=32;  K=20;  FOUT=50;  W=W1; }
        else if (idx < C3) { base=C2; Kp=64;  K=50;  FOUT=200; W=W2; }
        else if (idx < C4) { base=C3; Kp=224; K=200; FOUT=500; W=W3; }
        else if (idx < C5) { base=C4; Kp=512; K=500; FOUT=200; W=W4; }
        else               { base=C5; Kp=224; K=200; FOUT=100; W=W5; }
        int r = idx - base;
        int o = r / Kp;
        int k = r - o * Kp;
        float v = (o < FOUT && k < K) ? W[o * K + k] : 0.f;
        Split sp = split16(v);
        whi[idx] = sp.hi; wlo[idx] = sp.lo;
    } else if (idx < SW + BPTOT) {
        int b = idx - SW;
        const float* src; int FOUT; int o;
        if      (b < BP2)  { src=b1; FOUT=50;  o=b;        }
        else if (b < BP3)  { src=b2; FOUT=200; o=b-BP2;    }
        else if (b < BP4)  { src=b3; FOUT=500; o=b-BP3;    }
        else if (b < BP5)  { src=b4; FOUT=200; o=b-BP4;    }
        else               { src=b5; FOUT=100; o=b-BP5;    }
        biasP[b] = (o < FOUT) ? src[o] : 0.f;
    }
}

// ---------------- one MFMA layer ----------------
// Planes (LDS, stride STR halves): vhi, vlo (split v-state), dhi, ddh (fp16 d/dd).
// B-frag: lane l -> col = l&15 (sample), k0 = (l>>4)*8 + kt*32.
// A-frag (global W plane, row-major stride KP): lane l -> row = mt*16+(l&15).
// C/D: col(lane&15)=sample, row((lane>>4)*4+reg)=output neuron.
// Per (kt,mt): 5 MFMAs: v: Ahi*Bvh + Ahi*Bvl + Alo*Bvh ; d: Ahi*Bdh ; dd: Ahi*Bdd.
template<int KP, int MTILES, int NMT, int NWACT, int FOUT, bool TANH>
__device__ __forceinline__ void layer_mfma(
    const _Float16* __restrict__ Whi, const _Float16* __restrict__ Wlo,
    const float* __restrict__ biasP,
    _Float16* vhi, _Float16* vlo, _Float16* dhi, _Float16* ddh,
    int lane, int wv)
{
    constexpr int KT = KP / 32;
    const int colS = lane & 15;
    const int kg   = lane >> 4;
    const bool act = (wv < NWACT);

    f4 accv[NMT], accd[NMT], accdd[NMT];

    if (act) {
#pragma unroll
        for (int i = 0; i < NMT; ++i) {
            accv[i]  = (f4){0.f, 0.f, 0.f, 0.f};
            accd[i]  = (f4){0.f, 0.f, 0.f, 0.f};
            accdd[i] = (f4){0.f, 0.f, 0.f, 0.f};
        }

        const int boff = colS * STR + kg * 8;

        const _Float16* wbh[NMT];
        const _Float16* wbl[NMT];
#pragma unroll
        for (int i = 0; i < NMT; ++i) {
            int mt  = wv + NWACT * i;
            int mtc = mt < MTILES ? mt : MTILES - 1;
            int row = mtc * 16 + colS;
            wbh[i] = Whi + row * KP + kg * 8;
            wbl[i] = Wlo + row * KP + kg * 8;
        }

#pragma unroll
        for (int kt = 0; kt < KT; ++kt) {
            const int kb = kt * 32;
            h8 Bvh = *(const h8*)(vhi + boff + kb);
            h8 Bvl = *(const h8*)(vlo + boff + kb);
            h8 Bdh = *(const h8*)(dhi + boff + kb);
            h8 Bdd = *(const h8*)(ddh + boff + kb);
#pragma unroll
            for (int i = 0; i < NMT; ++i) {
                if (wv + NWACT * i < MTILES) {
                    h8 Ahi = *(const h8*)(wbh[i] + kb);
                    h8 Alo = *(const h8*)(wbl[i] + kb);
                    accv[i]  = __builtin_amdgcn_mfma_f32_16x16x32_f16(Ahi, Bvh, accv[i],  0, 0, 0);
                    accv[i]  = __builtin_amdgcn_mfma_f32_16x16x32_f16(Ahi, Bvl, accv[i],  0, 0, 0);
                    accv[i]  = __builtin_amdgcn_mfma_f32_16x16x32_f16(Alo, Bvh, accv[i],  0, 0, 0);
                    accd[i]  = __builtin_amdgcn_mfma_f32_16x16x32_f16(Ahi, Bdh, accd[i],  0, 0, 0);
                    accdd[i] = __builtin_amdgcn_mfma_f32_16x16x32_f16(Ahi, Bdd, accdd[i], 0, 0, 0);
                }
            }
        }
    }
    __syncthreads();   // all reads of planes complete before in-place overwrite

    if (act) {
#pragma unroll
        for (int i = 0; i < NMT; ++i) {
            int mt = wv + NWACT * i;
            if (mt < MTILES) {
                int o0 = mt * 16 + kg * 4;
                f4 bi = *(const f4*)(biasP + o0);
                h4 pvh, pvl, pdh, pdd;
#pragma unroll
                for (int r = 0; r < 4; ++r) {
                    float zv  = accv[i][r] + bi[r];
                    float zd  = accd[i][r];
                    float zdd = accdd[i][r];
                    float ov, od, odd;
                    if constexpr (TANH) {
                        float t  = fast_tanh(zv);
                        float s2 = 1.0f - t * t;
                        ov  = t;
                        od  = s2 * zd;
                        odd = s2 * zdd - 2.0f * t * s2 * zd * zd;
                    } else {
                        ov = zv; od = zd; odd = zdd;
                    }
                    if (o0 + r >= FOUT) { ov = 0.f; od = 0.f; odd = 0.f; }
                    Split sv = split16(ov);
                    pvh[r] = sv.hi; pvl[r] = sv.lo;
                    pdh[r] = (_Float16)od;
                    pdd[r] = (_Float16)odd;
                }
                int off = colS * STR + o0;
                *(h4*)(vhi + off) = pvh;
                *(h4*)(vlo + off) = pvl;
                *(h4*)(dhi + off) = pdh;
                *(h4*)(ddh + off) = pdd;
            }
        }
    }
    __syncthreads();
}

// ---------------- main fused kernel ----------------
__global__ __launch_bounds__(THREADS, 8) void pinn_mfma(
    const float* __restrict__ W0, const float* __restrict__ b0,
    const float* __restrict__ x,  const float* __restrict__ A,
    const float* __restrict__ bvec,
    const _Float16* __restrict__ whi, const float* __restrict__ biasP,
    float* __restrict__ out)
{
    __shared__ __align__(16) _Float16 smem[4 * BS * STR];   // 66,560 B
    __shared__ float xs[BS];

    _Float16* vhi = smem + 0 * BS * STR;
    _Float16* vlo = smem + 1 * BS * STR;
    _Float16* dhi = smem + 2 * BS * STR;
    _Float16* ddh = smem + 3 * BS * STR;
    // Fm/Um overlay the plane space after the last MFMA layer's barrier
    float* Fm = (float*)smem;              // 16 x 104 floats
    float* Um = Fm + BS * 104;

    const int tid  = threadIdx.x;
    const int bid  = blockIdx.x;
    const int lane = tid & 63;
    const int wv   = tid >> 6;
    const _Float16* wlo = whi + SW;

    if (tid < BS) xs[tid] = x[bid * BS + tid];
    __syncthreads();

    // ---- layer 0: 1 -> 20, write padded-K (32) input planes ----
    if (tid < 512) {
        int s = tid >> 5;       // 0..15
        int k = tid & 31;       // 0..31
        float v0 = 0.f, v1 = 0.f, v2 = 0.f;
        if (k < 20) {
            float w  = W0[k];
            float z  = w * xs[s] + b0[k];
            float t  = fast_tanh(z);
            float s2 = 1.0f - t * t;
            v0 = t; v1 = s2 * w; v2 = -2.0f * t * s2 * w * w;
        }
        Split s0 = split16(v0);
        int off = s * STR + k;
        vhi[off] = s0.hi;           vlo[off] = s0.lo;
        dhi[off] = (_Float16)v1;    ddh[off] = (_Float16)v2;
    }
    __syncthreads();

    //          KP   MT NMT NWA FOUT
    layer_mfma< 32,  4, 1,  4,  50, true>(whi + C1, wlo + C1, biasP + BP1, vhi, vlo, dhi, ddh, lane, wv);
    layer_mfma< 64, 14, 1, 14, 200, true>(whi + C2, wlo + C2, biasP + BP2, vhi, vlo, dhi, ddh, lane, wv);
    layer_mfma<224, 32, 2, 16, 500, true>(whi + C3, wlo + C3, biasP + BP3, vhi, vlo, dhi, ddh, lane, wv);
    layer_mfma<512, 14, 1, 14, 200, true>(whi + C4, wlo + C4, biasP + BP4, vhi, vlo, dhi, ddh, lane, wv);

    // ---- layer 5: 200 -> 100 linear, epilogue -> U, Uxx, F (overlay) ----
    {
        constexpr int KP = 224, KT = 7, MTILES = 7, NWACT = 7;
        const int colS = lane & 15;
        const int kg   = lane >> 4;
        const bool act = (wv < NWACT);
        f4 av = (f4){0.f,0.f,0.f,0.f}, ad = av, add = av;
        if (act) {
            const int boff = colS * STR + kg * 8;
            const _Float16* wb5h = whi + C5 + (wv*16 + colS)*KP + kg*8;
            const _Float16* wb5l = wlo + C5 + (wv*16 + colS)*KP + kg*8;
#pragma unroll
            for (int kt = 0; kt < KT; ++kt) {
                const int kb = kt * 32;
                h8 Bvh = *(const h8*)(vhi + boff + kb);
                h8 Bvl = *(const h8*)(vlo + boff + kb);
                h8 Bdh = *(const h8*)(dhi + boff + kb);
                h8 Bdd = *(const h8*)(ddh + boff + kb);
                h8 Ahi = *(const h8*)(wb5h + kb);
                h8 Alo = *(const h8*)(wb5l + kb);
                av  = __builtin_amdgcn_mfma_f32_16x16x32_f16(Ahi, Bvh, av,  0, 0, 0);
                av  = __builtin_amdgcn_mfma_f32_16x16x32_f16(Ahi, Bvl, av,  0, 0, 0);
                av  = __builtin_amdgcn_mfma_f32_16x16x32_f16(Alo, Bvh, av,  0, 0, 0);
                ad  = __builtin_amdgcn_mfma_f32_16x16x32_f16(Ahi, Bdh, ad,  0, 0, 0);
                add = __builtin_amdgcn_mfma_f32_16x16x32_f16(Ahi, Bdd, add, 0, 0, 0);
            }
        }
        __syncthreads();   // planes dead after this point; overlay Fm/Um
        if (act) {
            int o0 = wv * 16 + kg * 4;
            f4 bi = *(const f4*)(biasP + BP5 + o0);
            float xv = xs[colS];
            float xm = xv * xv - 1.0f;
#pragma unroll
            for (int r = 0; r < 4; ++r) {
                int q = o0 + r;
                if (q < Q) {
                    float gv  = av[r] + bi[r];
                    float gd  = ad[r];
                    float gdd = add[r];
                    float U   = -1.0f + xm * gv;
                    float Uxx = 2.0f * gv + 4.0f * xv * gd + xm * gdd;
                    float Fv  = 5.0f * U * U * U - 5.0f * U - 0.0005f * Uxx;
                    Fm[colS * 104 + q] = Fv;
                    Um[colS * 104 + q] = U;
                }
            }
        }
        __syncthreads();
    }

    // ---- tail: U0 = U + DT*F@A^T ; U1 = U0 - DT*(F@bvec^T) (fp32 vector) ----
    {
        int qc = tid & 63;          // candidate q (and q+64)
        int ss = tid >> 6;          // sample 0..15
        float accq[2] = {0.f, 0.f};
        float cb = 0.f;
        const float* Fr = Fm + ss * 104;
#pragma unroll 5
        for (int j = 0; j < Q; j += 4) {
            f4 f4v = *(const f4*)(Fr + j);
            f4 bv4 = *(const f4*)(bvec + j);
            cb += f4v[0]*bv4[0] + f4v[1]*bv4[1] + f4v[2]*bv4[2] + f4v[3]*bv4[3];
#pragma unroll
            for (int u = 0; u < 2; ++u) {
                int q   = qc + 64 * u;
                int qcl = q < Q ? q : Q - 1;
                f4 a4 = *(const f4*)(A + qcl * Q + j);
                accq[u] += f4v[0]*a4[0] + f4v[1]*a4[1] + f4v[2]*a4[2] + f4v[3]*a4[3];
            }
        }
        int sg = bid * BS + ss;
#pragma unroll
        for (int u = 0; u < 2; ++u) {
            int q = qc + 64 * u;
            if (q < Q) {
                float U0 = Um[ss * 104 + q] + DTC * accq[u];
                float U1 = U0 - DTC * cb;
                out[sg * Q + q] = U0;
                out[NSAMP * Q + sg * Q + q] = U1;
            }
        }
    }
}

extern "C" void kernel_launch(void* const* d_in, const int* in_sizes, int n_in,
                              void* d_out, int out_size, void* d_ws, size_t ws_size,
                              hipStream_t stream) {
    const float* W0 = (const float*)d_in[0];
    const float* b0 = (const float*)d_in[1];
    const float* W1 = (const float*)d_in[2];
    const float* b1 = (const float*)d_in[3];
    const float* W2 = (const float*)d_in[4];
    const float* b2 = (const float*)d_in[5];
    const float* W3 = (const float*)d_in[6];
    const float* b3 = (const float*)d_in[7];
    const float* W4 = (const float*)d_in[8];
    const float* b4 = (const float*)d_in[9];
    const float* W5 = (const float*)d_in[10];
    const float* b5 = (const float*)d_in[11];
    const float* x  = (const float*)d_in[12];
    const float* A  = (const float*)d_in[13];
    const float* bv = (const float*)d_in[14];
    float* out = (float*)d_out;

    _Float16* whi = (_Float16*)d_ws;
    float* biasP  = (float*)((char*)d_ws + WS_BIAS_BYTE_OFF);

    prepass<<<(SW + BPTOT + 255) / 256, 256, 0, stream>>>(
        W1, b1, W2, b2, W3, b3, W4, b4, W5, b5, whi, biasP);

    pinn_mfma<<<NSAMP / BS, THREADS, 0, stream>>>(
        W0, b0, x, A, bv, whi, biasP, out);
}

// Round 7
// 658.132 us; speedup vs baseline: 3.6716x; 1.0339x over previous
//
#include <hip/hip_runtime.h>
#include <hip/hip_bf16.h>

// PINN fused forward+jvp^2 via split-fp16 MFMA.
// R7: register diet to kill R5/R6's scratch spills under the 64-VGPR cap of
// __launch_bounds__(1024,8): (a) per-lane u32 element offsets against uniform
// SGPR weight bases instead of per-lane 64-bit pointer arrays (16->4 VGPRs);
// (b) #pragma unroll 2 on K-loops to bound in-flight load live ranges.
// Structure unchanged: 4 LDS planes (vhi,vlo,dhi,ddh), 2 blocks/CU,
// 5 MFMA per (kt,mt): v=3-product split-fp16, d/dd=plain fp16.

#define NSAMP 65536
#define Q     100
#define DTC   0.8f
#define BS    16
#define THREADS 1024
#define STR   520          // uniform plane stride (halves); fits KP<=512

typedef _Float16 h8 __attribute__((ext_vector_type(8)));
typedef _Float16 h4 __attribute__((ext_vector_type(4)));
typedef float    f4 __attribute__((ext_vector_type(4)));

// ---- padded weight-plane geometry (halves), Mp = max(ceil16(FOUT), Kp_next) ----
#define S1 (64*32)
#define S2 (224*64)
#define S3 (512*224)
#define S4 (224*512)
#define S5 (112*224)
#define SW (S1+S2+S3+S4+S5)      // 270848 halves per plane
#define C1 0
#define C2 (C1+S1)
#define C3 (C2+S2)
#define C4 (C3+S3)
#define C5 (C4+S4)
#define BP1 0
#define BP2 64
#define BP3 288
#define BP4 800
#define BP5 1024
#define BPTOT 1136
#define WS_BIAS_BYTE_OFF (SW*2*2)

__device__ __forceinline__ float fast_tanh(float z) {
    float az = fabsf(z);
    float e  = __expf(-2.0f * az);
    float r  = __builtin_amdgcn_rcpf(1.0f + e);
    float t  = (1.0f - e) * r;
    return copysignf(t, z);
}

struct Split { _Float16 hi, lo; };
__device__ __forceinline__ Split split16(float v) {
    Split s;
    s.hi = (_Float16)v;
    s.lo = (_Float16)(v - (float)s.hi);
    return s;
}

// ---------------- pre-pass: split/pad weights + biases into d_ws ----------------
__global__ __launch_bounds__(256) void prepass(
    const float* __restrict__ W1, const float* __restrict__ b1,
    const float* __restrict__ W2, const float* __restrict__ b2,
    const float* __restrict__ W3, const float* __restrict__ b3,
    const float* __restrict__ W4, const float* __restrict__ b4,
    const float* __restrict__ W5, const float* __restrict__ b5,
    _Float16* __restrict__ whi, float* __restrict__ biasP)
{
    int idx = blockIdx.x * 256 + threadIdx.x;
    _Float16* wlo = whi + SW;
    if (idx < SW) {
        int base, Kp, K, FOUT; const float* W;
        if      (idx < C2) { base=C1; Kp=32;  K=20;  FOUT=50;  W=W1; }
        else if (idx < C3) { base=C2; Kp=64;  K=50;  FOUT=200; W=W2; }
        else if (idx < C4) { base=C3; Kp=224; K=200; FOUT=500; W=W3; }
        else if (idx < C5) { base=C4; Kp=512; K=500; FOUT=200; W=W4; }
        else               { base=C5; Kp=224; K=200; FOUT=100; W=W5; }
        int r = idx - base;
        int o = r / Kp;
        int k = r - o * Kp;
        float v = (o < FOUT && k < K) ? W[o * K + k] : 0.f;
        Split sp = split16(v);
        whi[idx] = sp.hi; wlo[idx] = sp.lo;
    } else if (idx < SW + BPTOT) {
        int b = idx - SW;
        const float* src; int FOUT; int o;
        if      (b < BP2)  { src=b1; FOUT=50;  o=b;        }
        else if (b < BP3)  { src=b2; FOUT=200; o=b-BP2;    }
        else if (b < BP4)  { src=b3; FOUT=500; o=b-BP3;    }
        else if (b < BP5)  { src=b4; FOUT=200; o=b-BP4;    }
        else               { src=b5; FOUT=100; o=b-BP5;    }
        biasP[b] = (o < FOUT) ? src[o] : 0.f;
    }
}

// ---------------- one MFMA layer ----------------
// Planes (LDS, stride STR halves): vhi, vlo (split v-state), dhi, ddh (fp16 d/dd).
// B-frag: lane l -> col = l&15 (sample), k0 = (l>>4)*8 + kt*32.
// A-frag: u32 element offset WOFF+kb against uniform bases whi/wlo (saddr+voffset).
// C/D: col(lane&15)=sample, row((lane>>4)*4+reg)=output neuron.
// Per (kt,mt): 5 MFMAs: v: Ahi*Bvh + Ahi*Bvl + Alo*Bvh ; d: Ahi*Bdh ; dd: Ahi*Bdd.
template<int KP, int MTILES, int NMT, int NWACT, int FOUT, bool TANH>
__device__ __forceinline__ void layer_mfma(
    const _Float16* __restrict__ whi, const _Float16* __restrict__ wlo,
    int wcoff,                               // uniform element offset of this layer's plane
    const float* __restrict__ biasP,
    _Float16* vhi, _Float16* vlo, _Float16* dhi, _Float16* ddh,
    int lane, int wv)
{
    constexpr int KT = KP / 32;
    const int colS = lane & 15;
    const int kg   = lane >> 4;
    const bool act = (wv < NWACT);

    f4 accv[NMT], accd[NMT], accdd[NMT];

    if (act) {
#pragma unroll
        for (int i = 0; i < NMT; ++i) {
            accv[i]  = (f4){0.f, 0.f, 0.f, 0.f};
            accd[i]  = (f4){0.f, 0.f, 0.f, 0.f};
            accdd[i] = (f4){0.f, 0.f, 0.f, 0.f};
        }

        const int boff = colS * STR + kg * 8;

        unsigned woff[NMT];                 // u32 element offsets (4 VGPRs max)
#pragma unroll
        for (int i = 0; i < NMT; ++i) {
            int mt  = wv + NWACT * i;
            int mtc = mt < MTILES ? mt : MTILES - 1;
            woff[i] = (unsigned)(wcoff + (mtc * 16 + colS) * KP + kg * 8);
        }

#pragma unroll 2
        for (int kt = 0; kt < KT; ++kt) {
            const int kb = kt * 32;
            h8 Bvh = *(const h8*)(vhi + boff + kb);
            h8 Bvl = *(const h8*)(vlo + boff + kb);
            h8 Bdh = *(const h8*)(dhi + boff + kb);
            h8 Bdd = *(const h8*)(ddh + boff + kb);
#pragma unroll
            for (int i = 0; i < NMT; ++i) {
                if (wv + NWACT * i < MTILES) {
                    h8 Ahi = *(const h8*)(whi + woff[i] + kb);
                    h8 Alo = *(const h8*)(wlo + woff[i] + kb);
                    accv[i]  = __builtin_amdgcn_mfma_f32_16x16x32_f16(Ahi, Bvh, accv[i],  0, 0, 0);
                    accv[i]  = __builtin_amdgcn_mfma_f32_16x16x32_f16(Ahi, Bvl, accv[i],  0, 0, 0);
                    accv[i]  = __builtin_amdgcn_mfma_f32_16x16x32_f16(Alo, Bvh, accv[i],  0, 0, 0);
                    accd[i]  = __builtin_amdgcn_mfma_f32_16x16x32_f16(Ahi, Bdh, accd[i],  0, 0, 0);
                    accdd[i] = __builtin_amdgcn_mfma_f32_16x16x32_f16(Ahi, Bdd, accdd[i], 0, 0, 0);
                }
            }
        }
    }
    __syncthreads();   // all reads of planes complete before in-place overwrite

    if (act) {
#pragma unroll
        for (int i = 0; i < NMT; ++i) {
            int mt = wv + NWACT * i;
            if (mt < MTILES) {
                int o0 = mt * 16 + kg * 4;
                f4 bi = *(const f4*)(biasP + o0);
                h4 pvh, pvl, pdh, pdd;
#pragma unroll
                for (int r = 0; r < 4; ++r) {
                    float zv  = accv[i][r] + bi[r];
                    float zd  = accd[i][r];
                    float zdd = accdd[i][r];
                    float ov, od, odd;
                    if constexpr (TANH) {
                        float t  = fast_tanh(zv);
                        float s2 = 1.0f - t * t;
                        ov  = t;
                        od  = s2 * zd;
                        odd = s2 * zdd - 2.0f * t * s2 * zd * zd;
                    } else {
                        ov = zv; od = zd; odd = zdd;
                    }
                    if (o0 + r >= FOUT) { ov = 0.f; od = 0.f; odd = 0.f; }
                    Split sv = split16(ov);
                    pvh[r] = sv.hi; pvl[r] = sv.lo;
                    pdh[r] = (_Float16)od;
                    pdd[r] = (_Float16)odd;
                }
                int off = colS * STR + o0;
                *(h4*)(vhi + off) = pvh;
                *(h4*)(vlo + off) = pvl;
                *(h4*)(dhi + off) = pdh;
                *(h4*)(ddh + off) = pdd;
            }
        }
    }
    __syncthreads();
}

// ---------------- main fused kernel ----------------
__global__ __launch_bounds__(THREADS, 8) void pinn_mfma(
    const float* __restrict__ W0, const float* __restrict__ b0,
    const float* __restrict__ x,  const float* __restrict__ A,
    const float* __restrict__ bvec,
    const _Float16* __restrict__ whi, const float* __restrict__ biasP,
    float* __restrict__ out)
{
    __shared__ __align__(16) _Float16 smem[4 * BS * STR];   // 66,560 B
    __shared__ float xs[BS];

    _Float16* vhi = smem + 0 * BS * STR;
    _Float16* vlo = smem + 1 * BS * STR;
    _Float16* dhi = smem + 2 * BS * STR;
    _Float16* ddh = smem + 3 * BS * STR;
    // Fm/Um overlay the plane space after the last MFMA layer's barrier
    float* Fm = (float*)smem;              // 16 x 104 floats
    float* Um = Fm + BS * 104;

    const int tid  = threadIdx.x;
    const int bid  = blockIdx.x;
    const int lane = tid & 63;
    const int wv   = tid >> 6;
    const _Float16* wlo = whi + SW;

    if (tid < BS) xs[tid] = x[bid * BS + tid];
    __syncthreads();

    // ---- layer 0: 1 -> 20, write padded-K (32) input planes ----
    if (tid < 512) {
        int s = tid >> 5;       // 0..15
        int k = tid & 31;       // 0..31
        float v0 = 0.f, v1 = 0.f, v2 = 0.f;
        if (k < 20) {
            float w  = W0[k];
            float z  = w * xs[s] + b0[k];
            float t  = fast_tanh(z);
            float s2 = 1.0f - t * t;
            v0 = t; v1 = s2 * w; v2 = -2.0f * t * s2 * w * w;
        }
        Split s0 = split16(v0);
        int off = s * STR + k;
        vhi[off] = s0.hi;           vlo[off] = s0.lo;
        dhi[off] = (_Float16)v1;    ddh[off] = (_Float16)v2;
    }
    __syncthreads();

    //          KP   MT NMT NWA FOUT
    layer_mfma< 32,  4, 1,  4,  50, true>(whi, wlo, C1, biasP + BP1, vhi, vlo, dhi, ddh, lane, wv);
    layer_mfma< 64, 14, 1, 14, 200, true>(whi, wlo, C2, biasP + BP2, vhi, vlo, dhi, ddh, lane, wv);
    layer_mfma<224, 32, 2, 16, 500, true>(whi, wlo, C3, biasP + BP3, vhi, vlo, dhi, ddh, lane, wv);
    layer_mfma<512, 14, 1, 14, 200, true>(whi, wlo, C4, biasP + BP4, vhi, vlo, dhi, ddh, lane, wv);

    // ---- layer 5: 200 -> 100 linear, epilogue -> U, Uxx, F (overlay) ----
    {
        constexpr int KP = 224, KT = 7, MTILES = 7, NWACT = 7;
        const int colS = lane & 15;
        const int kg   = lane >> 4;
        const bool act = (wv < NWACT);
        f4 av = (f4){0.f,0.f,0.f,0.f}, ad = av, add = av;
        if (act) {
            const int boff = colS * STR + kg * 8;
            const unsigned w5off = (unsigned)(C5 + (wv*16 + colS)*KP + kg*8);
#pragma unroll 2
            for (int kt = 0; kt < KT; ++kt) {
                const int kb = kt * 32;
                h8 Bvh = *(const h8*)(vhi + boff + kb);
                h8 Bvl = *(const h8*)(vlo + boff + kb);
                h8 Bdh = *(const h8*)(dhi + boff + kb);
                h8 Bdd = *(const h8*)(ddh + boff + kb);
                h8 Ahi = *(const h8*)(whi + w5off + kb);
                h8 Alo = *(const h8*)(wlo + w5off + kb);
                av  = __builtin_amdgcn_mfma_f32_16x16x32_f16(Ahi, Bvh, av,  0, 0, 0);
                av  = __builtin_amdgcn_mfma_f32_16x16x32_f16(Ahi, Bvl, av,  0, 0, 0);
                av  = __builtin_amdgcn_mfma_f32_16x16x32_f16(Alo, Bvh, av,  0, 0, 0);
                ad  = __builtin_amdgcn_mfma_f32_16x16x32_f16(Ahi, Bdh, ad,  0, 0, 0);
                add = __builtin_amdgcn_mfma_f32_16x16x32_f16(Ahi, Bdd, add, 0, 0, 0);
            }
        }
        __syncthreads();   // planes dead after this point; overlay Fm/Um
        if (act) {
            int o0 = wv * 16 + kg * 4;
            f4 bi = *(const f4*)(biasP + BP5 + o0);
            float xv = xs[colS];
            float xm = xv * xv - 1.0f;
#pragma unroll
            for (int r = 0; r < 4; ++r) {
                int q = o0 + r;
                if (q < Q) {
                    float gv  = av[r] + bi[r];
                    float gd  = ad[r];
                    float gdd = add[r];
                    float U   = -1.0f + xm * gv;
                    float Uxx = 2.0f * gv + 4.0f * xv * gd + xm * gdd;
                    float Fv  = 5.0f * U * U * U - 5.0f * U - 0.0005f * Uxx;
                    Fm[colS * 104 + q] = Fv;
                    Um[colS * 104 + q] = U;
                }
            }
        }
        __syncthreads();
    }

    // ---- tail: U0 = U + DT*F@A^T ; U1 = U0 - DT*(F@bvec^T) (fp32 vector) ----
    {
        int qc = tid & 63;          // candidate q (and q+64)
        int ss = tid >> 6;          // sample 0..15
        float accq[2] = {0.f, 0.f};
        float cb = 0.f;
        const float* Fr = Fm + ss * 104;
#pragma unroll 5
        for (int j = 0; j < Q; j += 4) {
            f4 f4v = *(const f4*)(Fr + j);
            f4 bv4 = *(const f4*)(bvec + j);
            cb += f4v[0]*bv4[0] + f4v[1]*bv4[1] + f4v[2]*bv4[2] + f4v[3]*bv4[3];
#pragma unroll
            for (int u = 0; u < 2; ++u) {
                int q   = qc + 64 * u;
                int qcl = q < Q ? q : Q - 1;
                f4 a4 = *(const f4*)(A + qcl * Q + j);
                accq[u] += f4v[0]*a4[0] + f4v[1]*a4[1] + f4v[2]*a4[2] + f4v[3]*a4[3];
            }
        }
        int sg = bid * BS + ss;
#pragma unroll
        for (int u = 0; u < 2; ++u) {
            int q = qc + 64 * u;
            if (q < Q) {
                float U0 = Um[ss * 104 + q] + DTC * accq[u];
                float U1 = U0 - DTC * cb;
                out[sg * Q + q] = U0;
                out[NSAMP * Q + sg * Q + q] = U1;
            }
        }
    }
}

extern "C" void kernel_launch(void* const* d_in, const int* in_sizes, int n_in,
                              void* d_out, int out_size, void* d_ws, size_t ws_size,
                              hipStream_t stream) {
    const float* W0 = (const float*)d_in[0];
    const float* b0 = (const float*)d_in[1];
    const float* W1 = (const float*)d_in[2];
    const float* b1 = (const float*)d_in[3];
    const float* W2 = (const float*)d_in[4];
    const float* b2 = (const float*)d_in[5];
    const float* W3 = (const float*)d_in[6];
    const float* b3 = (const float*)d_in[7];
    const float* W4 = (const float*)d_in[8];
    const float* b4 = (const float*)d_in[9];
    const float* W5 = (const float*)d_in[10];
    const float* b5 = (const float*)d_in[11];
    const float* x  = (const float*)d_in[12];
    const float* A  = (const float*)d_in[13];
    const float* bv = (const float*)d_in[14];
    float* out = (float*)d_out;

    _Float16* whi = (_Float16*)d_ws;
    float* biasP  = (float*)((char*)d_ws + WS_BIAS_BYTE_OFF);

    prepass<<<(SW + BPTOT + 255) / 256, 256, 0, stream>>>(
        W1, b1, W2, b2, W3, b3, W4, b4, W5, b5, whi, biasP);

    pinn_mfma<<<NSAMP / BS, THREADS, 0, stream>>>(
        W0, b0, x, A, bv, whi, biasP, out);
}

// Round 8
// 636.838 us; speedup vs baseline: 3.7943x; 1.0334x over previous
//
#include <hip/hip_runtime.h>
#include <hip/hip_bf16.h>

// PINN fused forward+jvp^2 via split-fp16 MFMA.
// R8: 512-thread blocks + __launch_bounds__(512,4) -> 128 unified regs/wave
// (R7's 1024x8 shape allotted 64, which cannot hold acc+B+A+addr -> ~40MB/launch
// scratch spills). Still 2 blocks/CU (2x67KB LDS), now as two independent
// blocks so one block's barrier drain overlaps the other's MFMA.
// Per-wave m-tiles double (L3: NMT=4) -> B-plane LDS reads amortized 2x.
// Numerics unchanged: v = 3-product split-fp16, d/dd = plain fp16.

#define NSAMP 65536
#define Q     100
#define DTC   0.8f
#define BS    16
#define THREADS 512
#define STR   520          // uniform plane stride (halves); 520 % 64 == 8 (b128-friendly)

typedef _Float16 h8 __attribute__((ext_vector_type(8)));
typedef _Float16 h4 __attribute__((ext_vector_type(4)));
typedef float    f4 __attribute__((ext_vector_type(4)));

// ---- padded weight-plane geometry (halves), Mp = max(ceil16(FOUT), Kp_next) ----
#define S1 (64*32)
#define S2 (224*64)
#define S3 (512*224)
#define S4 (224*512)
#define S5 (112*224)
#define SW (S1+S2+S3+S4+S5)      // 270848 halves per plane
#define C1 0
#define C2 (C1+S1)
#define C3 (C2+S2)
#define C4 (C3+S3)
#define C5 (C4+S4)
#define BP1 0
#define BP2 64
#define BP3 288
#define BP4 800
#define BP5 1024
#define BPTOT 1136
#define WS_BIAS_BYTE_OFF (SW*2*2)

__device__ __forceinline__ float fast_tanh(float z) {
    float az = fabsf(z);
    float e  = __expf(-2.0f * az);
    float r  = __builtin_amdgcn_rcpf(1.0f + e);
    float t  = (1.0f - e) * r;
    return copysignf(t, z);
}

struct Split { _Float16 hi, lo; };
__device__ __forceinline__ Split split16(float v) {
    Split s;
    s.hi = (_Float16)v;
    s.lo = (_Float16)(v - (float)s.hi);
    return s;
}

// ---------------- pre-pass: split/pad weights + biases into d_ws ----------------
__global__ __launch_bounds__(256) void prepass(
    const float* __restrict__ W1, const float* __restrict__ b1,
    const float* __restrict__ W2, const float* __restrict__ b2,
    const float* __restrict__ W3, const float* __restrict__ b3,
    const float* __restrict__ W4, const float* __restrict__ b4,
    const float* __restrict__ W5, const float* __restrict__ b5,
    _Float16* __restrict__ whi, float* __restrict__ biasP)
{
    int idx = blockIdx.x * 256 + threadIdx.x;
    _Float16* wlo = whi + SW;
    if (idx < SW) {
        int base, Kp, K, FOUT; const float* W;
        if      (idx < C2) { base=C1; Kp=32;  K=20;  FOUT=50;  W=W1; }
        else if (idx < C3) { base=C2; Kp=64;  K=50;  FOUT=200; W=W2; }
        else if (idx < C4) { base=C3; Kp=224; K=200; FOUT=500; W=W3; }
        else if (idx < C5) { base=C4; Kp=512; K=500; FOUT=200; W=W4; }
        else               { base=C5; Kp=224; K=200; FOUT=100; W=W5; }
        int r = idx - base;
        int o = r / Kp;
        int k = r - o * Kp;
        float v = (o < FOUT && k < K) ? W[o * K + k] : 0.f;
        Split sp = split16(v);
        whi[idx] = sp.hi; wlo[idx] = sp.lo;
    } else if (idx < SW + BPTOT) {
        int b = idx - SW;
        const float* src; int FOUT; int o;
        if      (b < BP2)  { src=b1; FOUT=50;  o=b;        }
        else if (b < BP3)  { src=b2; FOUT=200; o=b-BP2;    }
        else if (b < BP4)  { src=b3; FOUT=500; o=b-BP3;    }
        else if (b < BP5)  { src=b4; FOUT=200; o=b-BP4;    }
        else               { src=b5; FOUT=100; o=b-BP5;    }
        biasP[b] = (o < FOUT) ? src[o] : 0.f;
    }
}

// ---------------- one MFMA layer ----------------
// Planes (LDS, stride STR halves): vhi, vlo (split v-state), dhi, ddh (fp16 d/dd).
// B-frag: lane l -> col = l&15 (sample), k0 = (l>>4)*8 + kt*32.
// A-frag: u32 element offset against uniform bases whi/wlo (saddr+voffset).
// C/D: col(lane&15)=sample, row((lane>>4)*4+reg)=output neuron.
// Per (kt,mt): 5 MFMAs: v: Ahi*Bvh + Ahi*Bvl + Alo*Bvh ; d: Ahi*Bdh ; dd: Ahi*Bdd.
template<int KP, int MTILES, int NMT, int NWACT, int FOUT, bool TANH>
__device__ __forceinline__ void layer_mfma(
    const _Float16* __restrict__ whi, const _Float16* __restrict__ wlo,
    int wcoff,                               // uniform element offset of this layer's plane
    const float* __restrict__ biasP,
    _Float16* vhi, _Float16* vlo, _Float16* dhi, _Float16* ddh,
    int lane, int wv)
{
    constexpr int KT = KP / 32;
    const int colS = lane & 15;
    const int kg   = lane >> 4;
    const bool act = (wv < NWACT);

    f4 accv[NMT], accd[NMT], accdd[NMT];

    if (act) {
#pragma unroll
        for (int i = 0; i < NMT; ++i) {
            accv[i]  = (f4){0.f, 0.f, 0.f, 0.f};
            accd[i]  = (f4){0.f, 0.f, 0.f, 0.f};
            accdd[i] = (f4){0.f, 0.f, 0.f, 0.f};
        }

        const int boff = colS * STR + kg * 8;

        unsigned woff[NMT];                 // u32 element offsets
#pragma unroll
        for (int i = 0; i < NMT; ++i) {
            int mt  = wv + NWACT * i;
            int mtc = mt < MTILES ? mt : MTILES - 1;
            woff[i] = (unsigned)(wcoff + (mtc * 16 + colS) * KP + kg * 8);
        }

#pragma unroll 2
        for (int kt = 0; kt < KT; ++kt) {
            const int kb = kt * 32;
            h8 Bvh = *(const h8*)(vhi + boff + kb);
            h8 Bvl = *(const h8*)(vlo + boff + kb);
            h8 Bdh = *(const h8*)(dhi + boff + kb);
            h8 Bdd = *(const h8*)(ddh + boff + kb);
#pragma unroll
            for (int i = 0; i < NMT; ++i) {
                if (wv + NWACT * i < MTILES) {
                    h8 Ahi = *(const h8*)(whi + woff[i] + kb);
                    h8 Alo = *(const h8*)(wlo + woff[i] + kb);
                    accv[i]  = __builtin_amdgcn_mfma_f32_16x16x32_f16(Ahi, Bvh, accv[i],  0, 0, 0);
                    accv[i]  = __builtin_amdgcn_mfma_f32_16x16x32_f16(Ahi, Bvl, accv[i],  0, 0, 0);
                    accv[i]  = __builtin_amdgcn_mfma_f32_16x16x32_f16(Alo, Bvh, accv[i],  0, 0, 0);
                    accd[i]  = __builtin_amdgcn_mfma_f32_16x16x32_f16(Ahi, Bdh, accd[i],  0, 0, 0);
                    accdd[i] = __builtin_amdgcn_mfma_f32_16x16x32_f16(Ahi, Bdd, accdd[i], 0, 0, 0);
                }
            }
        }
    }
    __syncthreads();   // all reads of planes complete before in-place overwrite

    if (act) {
#pragma unroll
        for (int i = 0; i < NMT; ++i) {
            int mt = wv + NWACT * i;
            if (mt < MTILES) {
                int o0 = mt * 16 + kg * 4;
                f4 bi = *(const f4*)(biasP + o0);
                h4 pvh, pvl, pdh, pdd;
#pragma unroll
                for (int r = 0; r < 4; ++r) {
                    float zv  = accv[i][r] + bi[r];
                    float zd  = accd[i][r];
                    float zdd = accdd[i][r];
                    float ov, od, odd;
                    if constexpr (TANH) {
                        float t  = fast_tanh(zv);
                        float s2 = 1.0f - t * t;
                        ov  = t;
                        od  = s2 * zd;
                        odd = s2 * zdd - 2.0f * t * s2 * zd * zd;
                    } else {
                        ov = zv; od = zd; odd = zdd;
                    }
                    if (o0 + r >= FOUT) { ov = 0.f; od = 0.f; odd = 0.f; }
                    Split sv = split16(ov);
                    pvh[r] = sv.hi; pvl[r] = sv.lo;
                    pdh[r] = (_Float16)od;
                    pdd[r] = (_Float16)odd;
                }
                int off = colS * STR + o0;
                *(h4*)(vhi + off) = pvh;
                *(h4*)(vlo + off) = pvl;
                *(h4*)(dhi + off) = pdh;
                *(h4*)(ddh + off) = pdd;
            }
        }
    }
    __syncthreads();
}

// ---------------- main fused kernel ----------------
__global__ __launch_bounds__(THREADS, 4) void pinn_mfma(
    const float* __restrict__ W0, const float* __restrict__ b0,
    const float* __restrict__ x,  const float* __restrict__ A,
    const float* __restrict__ bvec,
    const _Float16* __restrict__ whi, const float* __restrict__ biasP,
    float* __restrict__ out)
{
    __shared__ __align__(16) _Float16 smem[4 * BS * STR];   // 66,560 B
    __shared__ float xs[BS];

    _Float16* vhi = smem + 0 * BS * STR;
    _Float16* vlo = smem + 1 * BS * STR;
    _Float16* dhi = smem + 2 * BS * STR;
    _Float16* ddh = smem + 3 * BS * STR;
    // Fm/Um overlay the plane space after the last MFMA layer's barrier
    float* Fm = (float*)smem;              // 16 x 104 floats
    float* Um = Fm + BS * 104;

    const int tid  = threadIdx.x;
    const int bid  = blockIdx.x;
    const int lane = tid & 63;
    const int wv   = tid >> 6;
    const _Float16* wlo = whi + SW;

    if (tid < BS) xs[tid] = x[bid * BS + tid];
    __syncthreads();

    // ---- layer 0: 1 -> 20, write padded-K (32) input planes ----
    {
        int s = tid >> 5;       // 0..15
        int k = tid & 31;       // 0..31
        float v0 = 0.f, v1 = 0.f, v2 = 0.f;
        if (k < 20) {
            float w  = W0[k];
            float z  = w * xs[s] + b0[k];
            float t  = fast_tanh(z);
            float s2 = 1.0f - t * t;
            v0 = t; v1 = s2 * w; v2 = -2.0f * t * s2 * w * w;
        }
        Split s0 = split16(v0);
        int off = s * STR + k;
        vhi[off] = s0.hi;           vlo[off] = s0.lo;
        dhi[off] = (_Float16)v1;    ddh[off] = (_Float16)v2;
    }
    __syncthreads();

    //          KP   MT NMT NWA FOUT
    layer_mfma< 32,  4, 1,  4,  50, true>(whi, wlo, C1, biasP + BP1, vhi, vlo, dhi, ddh, lane, wv);
    layer_mfma< 64, 14, 2,  7, 200, true>(whi, wlo, C2, biasP + BP2, vhi, vlo, dhi, ddh, lane, wv);
    layer_mfma<224, 32, 4,  8, 500, true>(whi, wlo, C3, biasP + BP3, vhi, vlo, dhi, ddh, lane, wv);
    layer_mfma<512, 14, 2,  7, 200, true>(whi, wlo, C4, biasP + BP4, vhi, vlo, dhi, ddh, lane, wv);

    // ---- layer 5: 200 -> 100 linear, epilogue -> U, Uxx, F (overlay) ----
    {
        constexpr int KP = 224, KT = 7, MTILES = 7, NWACT = 7;
        const int colS = lane & 15;
        const int kg   = lane >> 4;
        const bool act = (wv < NWACT);
        f4 av = (f4){0.f,0.f,0.f,0.f}, ad = av, add = av;
        if (act) {
            const int boff = colS * STR + kg * 8;
            const unsigned w5off = (unsigned)(C5 + (wv*16 + colS)*KP + kg*8);
#pragma unroll 2
            for (int kt = 0; kt < KT; ++kt) {
                const int kb = kt * 32;
                h8 Bvh = *(const h8*)(vhi + boff + kb);
                h8 Bvl = *(const h8*)(vlo + boff + kb);
                h8 Bdh = *(const h8*)(dhi + boff + kb);
                h8 Bdd = *(const h8*)(ddh + boff + kb);
                h8 Ahi = *(const h8*)(whi + w5off + kb);
                h8 Alo = *(const h8*)(wlo + w5off + kb);
                av  = __builtin_amdgcn_mfma_f32_16x16x32_f16(Ahi, Bvh, av,  0, 0, 0);
                av  = __builtin_amdgcn_mfma_f32_16x16x32_f16(Ahi, Bvl, av,  0, 0, 0);
                av  = __builtin_amdgcn_mfma_f32_16x16x32_f16(Alo, Bvh, av,  0, 0, 0);
                ad  = __builtin_amdgcn_mfma_f32_16x16x32_f16(Ahi, Bdh, ad,  0, 0, 0);
                add = __builtin_amdgcn_mfma_f32_16x16x32_f16(Ahi, Bdd, add, 0, 0, 0);
            }
        }
        __syncthreads();   // planes dead after this point; overlay Fm/Um
        if (act) {
            int o0 = wv * 16 + kg * 4;
            f4 bi = *(const f4*)(biasP + BP5 + o0);
            float xv = xs[colS];
            float xm = xv * xv - 1.0f;
#pragma unroll
            for (int r = 0; r < 4; ++r) {
                int q = o0 + r;
                if (q < Q) {
                    float gv  = av[r] + bi[r];
                    float gd  = ad[r];
                    float gdd = add[r];
                    float U   = -1.0f + xm * gv;
                    float Uxx = 2.0f * gv + 4.0f * xv * gd + xm * gdd;
                    float Fv  = 5.0f * U * U * U - 5.0f * U - 0.0005f * Uxx;
                    Fm[colS * 104 + q] = Fv;
                    Um[colS * 104 + q] = U;
                }
            }
        }
        __syncthreads();
    }

    // ---- tail: U0 = U + DT*F@A^T ; U1 = U0 - DT*(F@bvec^T) (fp32 vector) ----
    {
        int qc = tid & 31;          // candidate q (and q+32, q+64, q+96)
        int ss = tid >> 5;          // sample 0..15
        float accq[4] = {0.f, 0.f, 0.f, 0.f};
        float cb = 0.f;
        const float* Fr = Fm + ss * 104;
#pragma unroll 5
        for (int j = 0; j < Q; j += 4) {
            f4 f4v = *(const f4*)(Fr + j);
            f4 bv4 = *(const f4*)(bvec + j);
            cb += f4v[0]*bv4[0] + f4v[1]*bv4[1] + f4v[2]*bv4[2] + f4v[3]*bv4[3];
#pragma unroll
            for (int u = 0; u < 4; ++u) {
                int q   = qc + 32 * u;
                int qcl = q < Q ? q : Q - 1;
                f4 a4 = *(const f4*)(A + qcl * Q + j);
                accq[u] += f4v[0]*a4[0] + f4v[1]*a4[1] + f4v[2]*a4[2] + f4v[3]*a4[3];
            }
        }
        int sg = bid * BS + ss;
#pragma unroll
        for (int u = 0; u < 4; ++u) {
            int q = qc + 32 * u;
            if (q < Q) {
                float U0 = Um[ss * 104 + q] + DTC * accq[u];
                float U1 = U0 - DTC * cb;
                out[sg * Q + q] = U0;
                out[NSAMP * Q + sg * Q + q] = U1;
            }
        }
    }
}

extern "C" void kernel_launch(void* const* d_in, const int* in_sizes, int n_in,
                              void* d_out, int out_size, void* d_ws, size_t ws_size,
                              hipStream_t stream) {
    const float* W0 = (const float*)d_in[0];
    const float* b0 = (const float*)d_in[1];
    const float* W1 = (const float*)d_in[2];
    const float* b1 = (const float*)d_in[3];
    const float* W2 = (const float*)d_in[4];
    const float* b2 = (const float*)d_in[5];
    const float* W3 = (const float*)d_in[6];
    const float* b3 = (const float*)d_in[7];
    const float* W4 = (const float*)d_in[8];
    const float* b4 = (const float*)d_in[9];
    const float* W5 = (const float*)d_in[10];
    const float* b5 = (const float*)d_in[11];
    const float* x  = (const float*)d_in[12];
    const float* A  = (const float*)d_in[13];
    const float* bv = (const float*)d_in[14];
    float* out = (float*)d_out;

    _Float16* whi = (_Float16*)d_ws;
    float* biasP  = (float*)((char*)d_ws + WS_BIAS_BYTE_OFF);

    prepass<<<(SW + BPTOT + 255) / 256, 256, 0, stream>>>(
        W1, b1, W2, b2, W3, b3, W4, b4, W5, b5, whi, biasP);

    pinn_mfma<<<NSAMP / BS, THREADS, 0, stream>>>(
        W0, b0, x, A, bv, whi, biasP, out);
}